// Round 1
// baseline (6072.815 us; speedup 1.0000x reference)
//
#include <hip/hip_runtime.h>

#define HID 256
#define IND 21
#define RT 32    // rows per block in the h-GEMM
#define KC 32    // K chunk staged in LDS
#define LDSP 36  // padded LDS row stride (floats): breaks 8-way write conflicts, keeps 16B align

// ---------------------------------------------------------------------------
// k1: x = relu(node_scalar @ W_in + b_in)   one block per node, 256 threads
// ---------------------------------------------------------------------------
__global__ __launch_bounds__(HID) void k_linear_in(
    const float* __restrict__ ns, const float* __restrict__ Win,
    const float* __restrict__ bin, float* __restrict__ x, int N) {
  __shared__ float s[IND];
  int node = blockIdx.x;
  if (node >= N) return;
  int c = threadIdx.x;
  if (c < IND) s[c] = ns[node * IND + c];
  __syncthreads();
  float acc = bin[c];
#pragma unroll
  for (int k = 0; k < IND; k++) acc += s[k] * Win[k * HID + c];
  x[node * HID + c] = acc > 0.f ? acc : 0.f;
}

// ---------------------------------------------------------------------------
// k2: scatter-add x[src] into agg[dst], degree count. One wave (64 lanes) per
// edge: float4 gather (1 KB row) + 4 f32 atomics per lane.
// ---------------------------------------------------------------------------
__global__ __launch_bounds__(256) void k_scatter(
    const float* __restrict__ x, const int* __restrict__ src,
    const int* __restrict__ dst, float* __restrict__ agg,
    float* __restrict__ deg, int E) {
  int wave = (int)((blockIdx.x * (unsigned)blockDim.x + threadIdx.x) >> 6);
  int lane = threadIdx.x & 63;
  if (wave >= E) return;
  int s = src[wave];
  int d = dst[wave];
  float4 v = *(const float4*)&x[(size_t)s * HID + lane * 4];
  float* ap = agg + (size_t)d * HID + lane * 4;
  atomicAdd(ap + 0, v.x);
  atomicAdd(ap + 1, v.y);
  atomicAdd(ap + 2, v.z);
  atomicAdd(ap + 3, v.w);
  if (lane == 0) atomicAdd(&deg[d], 1.0f);
}

// ---------------------------------------------------------------------------
// k3: h = relu(x@W_self + (agg/deg)@W_nei + b_self + b_nei); gsum[c] += sum_r h[r][c]
// 32 rows per block, 256 threads. Thread (rg=tid/64, lane=tid%64) owns
// rows rg*8..rg*8+7 and cols lane+{0,64,128,192}: 8x4 fp32 accumulators.
// K staged in LDS chunks of 32 (both x and normalized agg).
// ---------------------------------------------------------------------------
__global__ __launch_bounds__(256) void k_h(
    const float* __restrict__ x, const float* __restrict__ agg,
    const float* __restrict__ deg, const float* __restrict__ Wself,
    const float* __restrict__ Wnei, const float* __restrict__ bself,
    const float* __restrict__ bnei, float* __restrict__ gsum, int N) {
  __shared__ float xs[RT][LDSP];
  __shared__ float as[RT][LDSP];
  __shared__ float invd[RT];
  __shared__ float colsum[HID];
  int tid = threadIdx.x;
  int rowBase = blockIdx.x * RT;
  int lane = tid & 63;
  int rg = tid >> 6;

  if (tid < RT) {
    int rr = rowBase + tid;
    float d = (rr < N) ? deg[rr] : 1.0f;
    invd[tid] = 1.0f / fmaxf(d, 1.0f);
  }
  colsum[tid] = 0.f;  // blockDim == HID == 256

  float acc[8][4];
#pragma unroll
  for (int r = 0; r < 8; r++)
#pragma unroll
    for (int j = 0; j < 4; j++) acc[r][j] = 0.f;

  int lr = tid >> 3;            // 0..31 : row this thread stages
  int ko = (tid & 7) * 4;       // 0..28 : k-offset (float4)
  int srow = rowBase + lr;
  if (srow >= N) srow = N - 1;  // clamp (dead rows masked in epilogue)
  float ivs = 0.f;              // invd for staged row, read after first sync

  __syncthreads();
  ivs = invd[lr];

  for (int k0 = 0; k0 < HID; k0 += KC) {
    float4 xv = *(const float4*)&x[(size_t)srow * HID + k0 + ko];
    float4 av = *(const float4*)&agg[(size_t)srow * HID + k0 + ko];
    av.x *= ivs; av.y *= ivs; av.z *= ivs; av.w *= ivs;
    *(float4*)&xs[lr][ko] = xv;
    *(float4*)&as[lr][ko] = av;
    __syncthreads();

    for (int kk = 0; kk < KC; kk += 4) {
      float ws[4][4], wn[4][4];
#pragma unroll
      for (int j = 0; j < 4; j++) {
        int krow = (k0 + kk + j) * HID;
#pragma unroll
        for (int cj = 0; cj < 4; cj++) {
          int c = lane + 64 * cj;
          ws[j][cj] = Wself[krow + c];
          wn[j][cj] = Wnei[krow + c];
        }
      }
#pragma unroll
      for (int ri = 0; ri < 8; ri++) {
        int r2 = rg * 8 + ri;
        float4 xv2 = *(const float4*)&xs[r2][kk];
        float4 av2 = *(const float4*)&as[r2][kk];
#pragma unroll
        for (int cj = 0; cj < 4; cj++) {
          acc[ri][cj] += xv2.x * ws[0][cj] + av2.x * wn[0][cj];
          acc[ri][cj] += xv2.y * ws[1][cj] + av2.y * wn[1][cj];
          acc[ri][cj] += xv2.z * ws[2][cj] + av2.z * wn[2][cj];
          acc[ri][cj] += xv2.w * ws[3][cj] + av2.w * wn[3][cj];
        }
      }
    }
    __syncthreads();  // all reads of this chunk done before restaging
  }

  // epilogue: bias + relu, per-column partial sums
#pragma unroll
  for (int cj = 0; cj < 4; cj++) {
    int c = lane + 64 * cj;
    float b = bself[c] + bnei[c];
    float s = 0.f;
#pragma unroll
    for (int ri = 0; ri < 8; ri++) {
      int rr = rowBase + rg * 8 + ri;
      float h = acc[ri][cj] + b;
      h = h > 0.f ? h : 0.f;
      if (rr < N) s += h;
    }
    atomicAdd(&colsum[c], s);
  }
  __syncthreads();
  atomicAdd(&gsum[tid], colsum[tid]);
}

// ---------------------------------------------------------------------------
// k4: out = (gsum / N) @ W_out + b_out   single block, 256 threads
// ---------------------------------------------------------------------------
__global__ __launch_bounds__(HID) void k_out(
    const float* __restrict__ gsum, const float* __restrict__ Wout,
    const float* __restrict__ bout, float* __restrict__ out, float invN) {
  __shared__ float g[HID];
  int c = threadIdx.x;
  g[c] = gsum[c] * invN;
  __syncthreads();
  float acc = bout[c];
#pragma unroll 8
  for (int k = 0; k < HID; k++) acc += g[k] * Wout[k * HID + c];
  out[c] = acc;
}

extern "C" void kernel_launch(void* const* d_in, const int* in_sizes, int n_in,
                              void* d_out, int out_size, void* d_ws, size_t ws_size,
                              hipStream_t stream) {
  const float* ns    = (const float*)d_in[0];
  const float* Win   = (const float*)d_in[1];
  const float* bin   = (const float*)d_in[2];
  const float* Wself = (const float*)d_in[3];
  const float* bself = (const float*)d_in[4];
  const float* Wnei  = (const float*)d_in[5];
  const float* bnei  = (const float*)d_in[6];
  const float* Wout  = (const float*)d_in[7];
  const float* bout  = (const float*)d_in[8];
  const int*   eidx  = (const int*)d_in[9];

  int N = in_sizes[0] / IND;
  int E = in_sizes[9] / 2;
  const int* src = eidx;
  const int* dst = eidx + E;

  // workspace layout (fp32): x[N*HID] | agg[N*HID] | deg[N] | gsum[HID]
  float* x    = (float*)d_ws;
  float* agg  = x + (size_t)N * HID;
  float* deg  = agg + (size_t)N * HID;
  float* gsum = deg + N;

  hipMemsetAsync(agg, 0, (size_t)N * HID * sizeof(float), stream);
  hipMemsetAsync(deg, 0, (size_t)N * sizeof(float), stream);
  hipMemsetAsync(gsum, 0, HID * sizeof(float), stream);

  k_linear_in<<<N, HID, 0, stream>>>(ns, Win, bin, x, N);

  int waves_per_block = 256 / 64;
  int sgrid = (E + waves_per_block - 1) / waves_per_block;
  k_scatter<<<sgrid, 256, 0, stream>>>(x, src, dst, agg, deg, E);

  int hgrid = (N + RT - 1) / RT;
  k_h<<<hgrid, 256, 0, stream>>>(x, agg, deg, Wself, Wnei, bself, bnei, gsum, N);

  k_out<<<1, HID, 0, stream>>>(gsum, Wout, bout, (float*)d_out, 1.0f / (float)N);
}

// Round 2
// 1058.231 us; speedup vs baseline: 5.7386x; 5.7386x over previous
//
#include <hip/hip_runtime.h>

#define HID 256
#define IND 21
#define RT 32    // rows per block in the h-GEMM
#define KC 32    // K chunk staged in LDS
#define LDSP 36  // padded LDS row stride (floats)

// ---------------------------------------------------------------------------
// k1: x = relu(node_scalar @ W_in + b_in)   one block per node, 256 threads
// ---------------------------------------------------------------------------
__global__ __launch_bounds__(HID) void k_linear_in(
    const float* __restrict__ ns, const float* __restrict__ Win,
    const float* __restrict__ bin, float* __restrict__ x, int N) {
  __shared__ float s[IND];
  int node = blockIdx.x;
  if (node >= N) return;
  int c = threadIdx.x;
  if (c < IND) s[c] = ns[node * IND + c];
  __syncthreads();
  float acc = bin[c];
#pragma unroll
  for (int k = 0; k < IND; k++) acc += s[k] * Win[k * HID + c];
  x[node * HID + c] = acc > 0.f ? acc : 0.f;
}

// ---------------------------------------------------------------------------
// CSR build: histogram -> 3-step exclusive scan -> fill
// ---------------------------------------------------------------------------
__global__ __launch_bounds__(256) void k_hist(
    const int* __restrict__ dst, int* __restrict__ cnt, int E) {
  int e = blockIdx.x * 256 + threadIdx.x;
  if (e < E) atomicAdd(&cnt[dst[e]], 1);
}

// per-1024-chunk total
__global__ __launch_bounds__(256) void k_psum(
    const int* __restrict__ cnt, int* __restrict__ psum, int N) {
  __shared__ int ts[256];
  int tid = threadIdx.x;
  int base = blockIdx.x * 1024 + tid * 4;
  int t = 0;
#pragma unroll
  for (int j = 0; j < 4; j++) {
    int i = base + j;
    if (i < N) t += cnt[i];
  }
  ts[tid] = t;
  __syncthreads();
  for (int off = 128; off > 0; off >>= 1) {
    if (tid < off) ts[tid] += ts[tid + off];
    __syncthreads();
  }
  if (tid == 0) psum[blockIdx.x] = ts[0];
}

// exclusive scan of chunk totals (nb <= 128, serial in thread 0)
__global__ __launch_bounds__(64) void k_scan1(
    const int* __restrict__ psum, int* __restrict__ chunkoff, int nb) {
  if (threadIdx.x == 0) {
    int run = 0;
    for (int i = 0; i < nb; i++) { chunkoff[i] = run; run += psum[i]; }
  }
}

// per-chunk exclusive scan + chunk offset -> row_start, cursor
__global__ __launch_bounds__(256) void k_scan2(
    const int* __restrict__ cnt, const int* __restrict__ chunkoff,
    int* __restrict__ row_start, int* __restrict__ cursor, int N) {
  __shared__ int ts[256];
  int tid = threadIdx.x;
  int base = blockIdx.x * 1024 + tid * 4;
  int v[4];
  int tot = 0;
#pragma unroll
  for (int j = 0; j < 4; j++) {
    int i = base + j;
    v[j] = (i < N) ? cnt[i] : 0;
    tot += v[j];
  }
  ts[tid] = tot;
  __syncthreads();
  // Hillis-Steele inclusive scan over 256 thread totals
  for (int off = 1; off < 256; off <<= 1) {
    int t = (tid >= off) ? ts[tid - off] : 0;
    __syncthreads();
    ts[tid] += t;
    __syncthreads();
  }
  int run = chunkoff[blockIdx.x] + ts[tid] - tot;  // exclusive offset for this thread
#pragma unroll
  for (int j = 0; j < 4; j++) {
    int i = base + j;
    if (i < N) { row_start[i] = run; cursor[i] = run; run += v[j]; }
  }
}

__global__ __launch_bounds__(256) void k_fill(
    const int* __restrict__ src, const int* __restrict__ dst,
    int* __restrict__ cursor, int* __restrict__ csr, int E) {
  int e = blockIdx.x * 256 + threadIdx.x;
  if (e >= E) return;
  int d = dst[e];
  int pos = atomicAdd(&cursor[d], 1);
  csr[pos] = src[e];
}

// ---------------------------------------------------------------------------
// k_agg: one wave per node; gather x[src] rows via CSR, mean, write agg.
// 64 lanes x float4 = full 1KB row per edge iteration. No atomics.
// ---------------------------------------------------------------------------
__global__ __launch_bounds__(256) void k_agg(
    const float* __restrict__ x, const int* __restrict__ csr,
    const int* __restrict__ row_start, const int* __restrict__ cnt,
    float* __restrict__ agg, int N) {
  int wid = (int)((blockIdx.x * (unsigned)blockDim.x + threadIdx.x) >> 6);
  int lane = threadIdx.x & 63;
  if (wid >= N) return;
  int start = row_start[wid];
  int c = cnt[wid];
  float a0 = 0.f, a1 = 0.f, a2 = 0.f, a3 = 0.f;
  for (int i = 0; i < c; i++) {
    int s = csr[start + i];
    float4 v = *(const float4*)&x[(size_t)s * HID + lane * 4];
    a0 += v.x; a1 += v.y; a2 += v.z; a3 += v.w;
  }
  float inv = 1.0f / fmaxf((float)c, 1.0f);
  float4 o;
  o.x = a0 * inv; o.y = a1 * inv; o.z = a2 * inv; o.w = a3 * inv;
  *(float4*)&agg[(size_t)wid * HID + lane * 4] = o;
}

// ---------------------------------------------------------------------------
// k_h: h = relu(x@W_self + agg@W_nei + b); gsum[c] += sum_r h[r][c]
// agg is pre-normalized. 32 rows/block, 8x4 fp32 acc per thread.
// ---------------------------------------------------------------------------
__global__ __launch_bounds__(256) void k_h(
    const float* __restrict__ x, const float* __restrict__ agg,
    const float* __restrict__ Wself, const float* __restrict__ Wnei,
    const float* __restrict__ bself, const float* __restrict__ bnei,
    float* __restrict__ gsum, int N) {
  __shared__ float xs[RT][LDSP];
  __shared__ float as[RT][LDSP];
  __shared__ float colsum[HID];
  int tid = threadIdx.x;
  int rowBase = blockIdx.x * RT;
  int lane = tid & 63;
  int rg = tid >> 6;

  colsum[tid] = 0.f;

  float acc[8][4];
#pragma unroll
  for (int r = 0; r < 8; r++)
#pragma unroll
    for (int j = 0; j < 4; j++) acc[r][j] = 0.f;

  int lr = tid >> 3;            // 0..31 : row this thread stages
  int ko = (tid & 7) * 4;       // 0..28 : k-offset (float4)
  int srow = rowBase + lr;
  if (srow >= N) srow = N - 1;  // clamp (dead rows masked in epilogue)

  for (int k0 = 0; k0 < HID; k0 += KC) {
    float4 xv = *(const float4*)&x[(size_t)srow * HID + k0 + ko];
    float4 av = *(const float4*)&agg[(size_t)srow * HID + k0 + ko];
    *(float4*)&xs[lr][ko] = xv;
    *(float4*)&as[lr][ko] = av;
    __syncthreads();

    for (int kk = 0; kk < KC; kk += 4) {
      float ws[4][4], wn[4][4];
#pragma unroll
      for (int j = 0; j < 4; j++) {
        int krow = (k0 + kk + j) * HID;
#pragma unroll
        for (int cj = 0; cj < 4; cj++) {
          int c = lane + 64 * cj;
          ws[j][cj] = Wself[krow + c];
          wn[j][cj] = Wnei[krow + c];
        }
      }
#pragma unroll
      for (int ri = 0; ri < 8; ri++) {
        int r2 = rg * 8 + ri;
        float4 xv2 = *(const float4*)&xs[r2][kk];
        float4 av2 = *(const float4*)&as[r2][kk];
#pragma unroll
        for (int cj = 0; cj < 4; cj++) {
          acc[ri][cj] += xv2.x * ws[0][cj] + av2.x * wn[0][cj];
          acc[ri][cj] += xv2.y * ws[1][cj] + av2.y * wn[1][cj];
          acc[ri][cj] += xv2.z * ws[2][cj] + av2.z * wn[2][cj];
          acc[ri][cj] += xv2.w * ws[3][cj] + av2.w * wn[3][cj];
        }
      }
    }
    __syncthreads();
  }

  // epilogue: bias + relu, per-column partial sums
#pragma unroll
  for (int cj = 0; cj < 4; cj++) {
    int c = lane + 64 * cj;
    float b = bself[c] + bnei[c];
    float s = 0.f;
#pragma unroll
    for (int ri = 0; ri < 8; ri++) {
      int rr = rowBase + rg * 8 + ri;
      float h = acc[ri][cj] + b;
      h = h > 0.f ? h : 0.f;
      if (rr < N) s += h;
    }
    atomicAdd(&colsum[c], s);
  }
  __syncthreads();
  atomicAdd(&gsum[tid], colsum[tid]);
}

// ---------------------------------------------------------------------------
// k_out: out = (gsum / N) @ W_out + b_out   single block, 256 threads
// ---------------------------------------------------------------------------
__global__ __launch_bounds__(HID) void k_out(
    const float* __restrict__ gsum, const float* __restrict__ Wout,
    const float* __restrict__ bout, float* __restrict__ out, float invN) {
  __shared__ float g[HID];
  int c = threadIdx.x;
  g[c] = gsum[c] * invN;
  __syncthreads();
  float acc = bout[c];
#pragma unroll 8
  for (int k = 0; k < HID; k++) acc += g[k] * Wout[k * HID + c];
  out[c] = acc;
}

extern "C" void kernel_launch(void* const* d_in, const int* in_sizes, int n_in,
                              void* d_out, int out_size, void* d_ws, size_t ws_size,
                              hipStream_t stream) {
  const float* ns    = (const float*)d_in[0];
  const float* Win   = (const float*)d_in[1];
  const float* bin   = (const float*)d_in[2];
  const float* Wself = (const float*)d_in[3];
  const float* bself = (const float*)d_in[4];
  const float* Wnei  = (const float*)d_in[5];
  const float* bnei  = (const float*)d_in[6];
  const float* Wout  = (const float*)d_in[7];
  const float* bout  = (const float*)d_in[8];
  const int*   eidx  = (const int*)d_in[9];

  int N = in_sizes[0] / IND;
  int E = in_sizes[9] / 2;
  const int* src = eidx;
  const int* dst = eidx + E;

  // workspace layout: x[N*H] f | agg[N*H] f | csr[E] i | cnt[N] i |
  //                   row_start[N] i | cursor[N] i | chunkoff[128] i | gsum[H] f
  float* x   = (float*)d_ws;
  float* agg = x + (size_t)N * HID;
  int* csr       = (int*)(agg + (size_t)N * HID);
  int* cnt       = csr + E;
  int* row_start = cnt + N;
  int* cursor    = row_start + N;
  int* chunkoff  = cursor + N;
  float* gsum    = (float*)(chunkoff + 128);

  hipMemsetAsync(cnt, 0, (size_t)N * sizeof(int), stream);
  hipMemsetAsync(gsum, 0, HID * sizeof(float), stream);

  k_linear_in<<<N, HID, 0, stream>>>(ns, Win, bin, x, N);

  int egrid = (E + 255) / 256;
  k_hist<<<egrid, 256, 0, stream>>>(dst, cnt, E);

  int nb = (N + 1023) / 1024;
  k_psum<<<nb, 256, 0, stream>>>(cnt, cursor /*reuse as psum scratch*/, N);
  k_scan1<<<1, 64, 0, stream>>>(cursor, chunkoff, nb);
  k_scan2<<<nb, 256, 0, stream>>>(cnt, chunkoff, row_start, cursor, N);

  k_fill<<<egrid, 256, 0, stream>>>(src, dst, cursor, csr, E);

  int agrid = (N + 3) / 4;  // one wave per node, 4 waves/block
  k_agg<<<agrid, 256, 0, stream>>>(x, csr, row_start, cnt, agg, N);

  int hgrid = (N + RT - 1) / RT;
  k_h<<<hgrid, 256, 0, stream>>>(x, agg, Wself, Wnei, bself, bnei, gsum, N);

  k_out<<<1, HID, 0, stream>>>(gsum, Wout, bout, (float*)d_out, 1.0f / (float)N);
}

// Round 3
// 605.021 us; speedup vs baseline: 10.0374x; 1.7491x over previous
//
#include <hip/hip_runtime.h>
#include <hip/hip_bf16.h>

#define HID 256
#define IND 21
#define ASTR 40   // LDS row stride in bf16 elems (80 B): 2-way bank conflicts only, 16B-aligned

typedef short short8 __attribute__((ext_vector_type(8)));
typedef float floatx4 __attribute__((ext_vector_type(4)));

__device__ inline float bf2f(unsigned short u) {
  union { unsigned int i; float f; } c;
  c.i = ((unsigned int)u) << 16;
  return c.f;
}
__device__ inline unsigned short f2bf(float f) {
  __hip_bfloat16 h = __float2bfloat16(f);  // RNE
  union { __hip_bfloat16 h; unsigned short u; } c;
  c.h = h;
  return c.u;
}

// ---------------------------------------------------------------------------
// k1: xb = bf16(relu(node_scalar @ W_in + b_in))  one block/node, 256 threads
// ---------------------------------------------------------------------------
__global__ __launch_bounds__(HID) void k_linear_in(
    const float* __restrict__ ns, const float* __restrict__ Win,
    const float* __restrict__ bin, unsigned short* __restrict__ xb, int N) {
  __shared__ float s[IND];
  int node = blockIdx.x;
  if (node >= N) return;
  int c = threadIdx.x;
  if (c < IND) s[c] = ns[node * IND + c];
  __syncthreads();
  float acc = bin[c];
#pragma unroll
  for (int k = 0; k < IND; k++) acc += s[k] * Win[k * HID + c];
  xb[(size_t)node * HID + c] = f2bf(acc > 0.f ? acc : 0.f);
}

// ---------------------------------------------------------------------------
// weight prep: WcT[n][k] = bf16( k<256 ? Wself[k][n] : Wnei[k-256][n] )
// ---------------------------------------------------------------------------
__global__ __launch_bounds__(512) void k_wconv(
    const float* __restrict__ Wself, const float* __restrict__ Wnei,
    unsigned short* __restrict__ WcT) {
  int n = blockIdx.x;   // 0..255
  int k = threadIdx.x;  // 0..511
  float v = (k < HID) ? Wself[k * HID + n] : Wnei[(k - HID) * HID + n];
  WcT[n * 512 + k] = f2bf(v);
}

// ---------------------------------------------------------------------------
// CSR build: histogram -> scan -> fill
// ---------------------------------------------------------------------------
__global__ __launch_bounds__(256) void k_hist(
    const int* __restrict__ dst, int* __restrict__ cnt, int E) {
  int e = blockIdx.x * 256 + threadIdx.x;
  if (e < E) atomicAdd(&cnt[dst[e]], 1);
}

__global__ __launch_bounds__(256) void k_psum(
    const int* __restrict__ cnt, int* __restrict__ psum, int N) {
  __shared__ int ts[256];
  int tid = threadIdx.x;
  int base = blockIdx.x * 1024 + tid * 4;
  int t = 0;
#pragma unroll
  for (int j = 0; j < 4; j++) {
    int i = base + j;
    if (i < N) t += cnt[i];
  }
  ts[tid] = t;
  __syncthreads();
  for (int off = 128; off > 0; off >>= 1) {
    if (tid < off) ts[tid] += ts[tid + off];
    __syncthreads();
  }
  if (tid == 0) psum[blockIdx.x] = ts[0];
}

__global__ __launch_bounds__(64) void k_scan1(
    const int* __restrict__ psum, int* __restrict__ chunkoff, int nb) {
  if (threadIdx.x == 0) {
    int run = 0;
    for (int i = 0; i < nb; i++) { chunkoff[i] = run; run += psum[i]; }
  }
}

__global__ __launch_bounds__(256) void k_scan2(
    const int* __restrict__ cnt, const int* __restrict__ chunkoff,
    int* __restrict__ row_start, int* __restrict__ cursor, int N) {
  __shared__ int ts[256];
  int tid = threadIdx.x;
  int base = blockIdx.x * 1024 + tid * 4;
  int v[4];
  int tot = 0;
#pragma unroll
  for (int j = 0; j < 4; j++) {
    int i = base + j;
    v[j] = (i < N) ? cnt[i] : 0;
    tot += v[j];
  }
  ts[tid] = tot;
  __syncthreads();
  for (int off = 1; off < 256; off <<= 1) {
    int t = (tid >= off) ? ts[tid - off] : 0;
    __syncthreads();
    ts[tid] += t;
    __syncthreads();
  }
  int run = chunkoff[blockIdx.x] + ts[tid] - tot;
#pragma unroll
  for (int j = 0; j < 4; j++) {
    int i = base + j;
    if (i < N) { row_start[i] = run; cursor[i] = run; run += v[j]; }
  }
}

__global__ __launch_bounds__(256) void k_fill(
    const int* __restrict__ src, const int* __restrict__ dst,
    int* __restrict__ cursor, int* __restrict__ csr, int E) {
  int e = blockIdx.x * 256 + threadIdx.x;
  if (e >= E) return;
  int d = dst[e];
  int pos = atomicAdd(&cursor[d], 1);
  csr[pos] = src[e];
}

// ---------------------------------------------------------------------------
// k_agg: one wave per node; gather bf16 x rows via CSR, fp32 accumulate,
// write bf16 mean. 64 lanes x ushort4 (8 B) = full 512 B row per edge.
// ---------------------------------------------------------------------------
__global__ __launch_bounds__(256) void k_agg(
    const unsigned short* __restrict__ xb, const int* __restrict__ csr,
    const int* __restrict__ row_start, const int* __restrict__ cnt,
    unsigned short* __restrict__ aggb, int N) {
  int wid = (int)((blockIdx.x * (unsigned)blockDim.x + threadIdx.x) >> 6);
  int lane = threadIdx.x & 63;
  if (wid >= N) return;
  int start = row_start[wid];
  int c = cnt[wid];
  float a0 = 0.f, a1 = 0.f, a2 = 0.f, a3 = 0.f;
  for (int i = 0; i < c; i++) {
    int s = csr[start + i];
    ushort4 v = *(const ushort4*)&xb[(size_t)s * HID + lane * 4];
    a0 += bf2f(v.x); a1 += bf2f(v.y); a2 += bf2f(v.z); a3 += bf2f(v.w);
  }
  float inv = 1.0f / fmaxf((float)c, 1.0f);
  ushort4 o;
  o.x = f2bf(a0 * inv); o.y = f2bf(a1 * inv);
  o.z = f2bf(a2 * inv); o.w = f2bf(a3 * inv);
  *(ushort4*)&aggb[(size_t)wid * HID + lane * 4] = o;
}

// ---------------------------------------------------------------------------
// k_h: gsum[c] += sum_rows relu( [x|agg] @ WcT^T + bself + bnei )
// MFMA bf16 16x16x32. Block tile 128 rows x 128 cols, 4 waves 2x2, each wave
// 64x64 = 4x4 MFMA tiles (64 acc VGPRs). K=512 in chunks of 32 staged in LDS
// (stride 40 bf16 = 2-way conflicts only). h is never written to memory.
// ---------------------------------------------------------------------------
__global__ __launch_bounds__(256) void k_h(
    const unsigned short* __restrict__ xb, const unsigned short* __restrict__ aggb,
    const unsigned short* __restrict__ WcT, const float* __restrict__ bself,
    const float* __restrict__ bnei, float* __restrict__ gsum, int N) {
  __shared__ __align__(16) unsigned short As[128 * ASTR];
  __shared__ __align__(16) unsigned short Bs[128 * ASTR];
  __shared__ float colsum[128];
  int tid = threadIdx.x;
  int rowBase = blockIdx.x * 128;
  int colBase = blockIdx.y * 128;
  int lane = tid & 63;
  int wid = tid >> 6;
  int wr = wid >> 1, wc = wid & 1;
  int n16 = lane & 15, quad = lane >> 4;

  if (tid < 128) colsum[tid] = 0.f;

  floatx4 acc[4][4];
#pragma unroll
  for (int i = 0; i < 4; i++)
#pragma unroll
    for (int j = 0; j < 4; j++) acc[i][j] = (floatx4){0.f, 0.f, 0.f, 0.f};

  for (int k0 = 0; k0 < 512; k0 += 32) {
    const unsigned short* abase = (k0 < HID) ? xb : aggb;
    int kc = (k0 < HID) ? k0 : (k0 - HID);
    // stage A (128x32) and B (128 cols x 32 k) as uint4 (8 bf16) pieces
#pragma unroll
    for (int j = 0; j < 2; j++) {
      int idx = tid + j * 256;     // 0..511
      int r = idx >> 2;            // 0..127
      int s = idx & 3;             // 16B segment
      int gr = rowBase + r;
      if (gr >= N) gr = N - 1;
      uint4 va = *(const uint4*)(abase + (size_t)gr * HID + kc + s * 8);
      *(uint4*)(&As[r * ASTR + s * 8]) = va;
      uint4 vb = *(const uint4*)(WcT + (size_t)(colBase + r) * 512 + k0 + s * 8);
      *(uint4*)(&Bs[r * ASTR + s * 8]) = vb;
    }
    __syncthreads();

    short8 af[4], bfr[4];
#pragma unroll
    for (int rt = 0; rt < 4; rt++)
      af[rt] = *(const short8*)&As[(wr * 64 + rt * 16 + n16) * ASTR + quad * 8];
#pragma unroll
    for (int ct = 0; ct < 4; ct++)
      bfr[ct] = *(const short8*)&Bs[(wc * 64 + ct * 16 + n16) * ASTR + quad * 8];
#pragma unroll
    for (int rt = 0; rt < 4; rt++)
#pragma unroll
      for (int ct = 0; ct < 4; ct++)
        acc[rt][ct] = __builtin_amdgcn_mfma_f32_16x16x32_bf16(
            af[rt], bfr[ct], acc[rt][ct], 0, 0, 0);
    __syncthreads();
  }

  // epilogue: bias + relu + row-masked column sums (C/D: col=lane&15, row=quad*4+reg)
#pragma unroll
  for (int ct = 0; ct < 4; ct++) {
    int lcol = wc * 64 + ct * 16 + n16;
    int gcol = colBase + lcol;
    float b = bself[gcol] + bnei[gcol];
    float psum = 0.f;
#pragma unroll
    for (int rt = 0; rt < 4; rt++) {
#pragma unroll
      for (int r = 0; r < 4; r++) {
        int row = rowBase + wr * 64 + rt * 16 + quad * 4 + r;
        float v = acc[rt][ct][r] + b;
        v = v > 0.f ? v : 0.f;
        if (row < N) psum += v;
      }
    }
    atomicAdd(&colsum[lcol], psum);
  }
  __syncthreads();
  if (tid < 128) atomicAdd(&gsum[colBase + tid], colsum[tid]);
}

// ---------------------------------------------------------------------------
// k_out: out = (gsum / N) @ W_out + b_out   single block, 256 threads
// ---------------------------------------------------------------------------
__global__ __launch_bounds__(HID) void k_out(
    const float* __restrict__ gsum, const float* __restrict__ Wout,
    const float* __restrict__ bout, float* __restrict__ out, float invN) {
  __shared__ float g[HID];
  int c = threadIdx.x;
  g[c] = gsum[c] * invN;
  __syncthreads();
  float acc = bout[c];
#pragma unroll 8
  for (int k = 0; k < HID; k++) acc += g[k] * Wout[k * HID + c];
  out[c] = acc;
}

extern "C" void kernel_launch(void* const* d_in, const int* in_sizes, int n_in,
                              void* d_out, int out_size, void* d_ws, size_t ws_size,
                              hipStream_t stream) {
  const float* ns    = (const float*)d_in[0];
  const float* Win   = (const float*)d_in[1];
  const float* bin   = (const float*)d_in[2];
  const float* Wself = (const float*)d_in[3];
  const float* bself = (const float*)d_in[4];
  const float* Wnei  = (const float*)d_in[5];
  const float* bnei  = (const float*)d_in[6];
  const float* Wout  = (const float*)d_in[7];
  const float* bout  = (const float*)d_in[8];
  const int*   eidx  = (const int*)d_in[9];

  int N = in_sizes[0] / IND;
  int E = in_sizes[9] / 2;
  const int* src = eidx;
  const int* dst = eidx + E;

  // ws layout: xb[N*H] bf16 | aggb[N*H] bf16 | WcT[256*512] bf16 | csr[E] i |
  //            cnt[N] i | row_start[N] i | cursor[N] i | chunkoff[128] i | gsum[H] f
  unsigned short* xb   = (unsigned short*)d_ws;
  unsigned short* aggb = xb + (size_t)N * HID;
  unsigned short* WcT  = aggb + (size_t)N * HID;
  int* csr       = (int*)(WcT + 256 * 512);
  int* cnt       = csr + E;
  int* row_start = cnt + N;
  int* cursor    = row_start + N;
  int* chunkoff  = cursor + N;
  float* gsum    = (float*)(chunkoff + 128);

  hipMemsetAsync(cnt, 0, (size_t)N * sizeof(int), stream);
  hipMemsetAsync(gsum, 0, HID * sizeof(float), stream);

  k_linear_in<<<N, HID, 0, stream>>>(ns, Win, bin, xb, N);
  k_wconv<<<256, 512, 0, stream>>>(Wself, Wnei, WcT);

  int egrid = (E + 255) / 256;
  k_hist<<<egrid, 256, 0, stream>>>(dst, cnt, E);

  int nb = (N + 1023) / 1024;
  k_psum<<<nb, 256, 0, stream>>>(cnt, cursor, N);
  k_scan1<<<1, 64, 0, stream>>>(cursor, chunkoff, nb);
  k_scan2<<<nb, 256, 0, stream>>>(cnt, chunkoff, row_start, cursor, N);

  k_fill<<<egrid, 256, 0, stream>>>(src, dst, cursor, csr, E);

  int agrid = (N + 3) / 4;
  k_agg<<<agrid, 256, 0, stream>>>(xb, csr, row_start, cnt, aggb, N);

  dim3 hgrid((N + 127) / 128, 2);
  k_h<<<hgrid, 256, 0, stream>>>(xb, aggb, WcT, bself, bnei, gsum, N);

  k_out<<<1, HID, 0, stream>>>(gsum, Wout, bout, (float*)d_out, 1.0f / (float)N);
}

// Round 4
// 545.432 us; speedup vs baseline: 11.1339x; 1.1093x over previous
//
#include <hip/hip_runtime.h>
#include <hip/hip_bf16.h>

#define HID 256
#define IND 21
#define ASTR 40   // LDS row stride in bf16 elems (80 B): 2-way bank conflicts only

typedef short short8 __attribute__((ext_vector_type(8)));
typedef float floatx4 __attribute__((ext_vector_type(4)));

__device__ inline float bf2f(unsigned short u) {
  union { unsigned int i; float f; } c;
  c.i = ((unsigned int)u) << 16;
  return c.f;
}
__device__ inline float bflo(unsigned int u) {
  union { unsigned int i; float f; } c; c.i = u << 16; return c.f;
}
__device__ inline float bfhi(unsigned int u) {
  union { unsigned int i; float f; } c; c.i = u & 0xffff0000u; return c.f;
}
__device__ inline unsigned short f2bf(float f) {
  __hip_bfloat16 h = __float2bfloat16(f);  // RNE
  union { __hip_bfloat16 h; unsigned short u; } c;
  c.h = h;
  return c.u;
}

// ---------------------------------------------------------------------------
// k1: xb = bf16(relu(node_scalar @ W_in + b_in))  one block/node, 256 threads
// ---------------------------------------------------------------------------
__global__ __launch_bounds__(HID) void k_linear_in(
    const float* __restrict__ ns, const float* __restrict__ Win,
    const float* __restrict__ bin, unsigned short* __restrict__ xb, int N) {
  __shared__ float s[IND];
  int node = blockIdx.x;
  if (node >= N) return;
  int c = threadIdx.x;
  if (c < IND) s[c] = ns[node * IND + c];
  __syncthreads();
  float acc = bin[c];
#pragma unroll
  for (int k = 0; k < IND; k++) acc += s[k] * Win[k * HID + c];
  xb[(size_t)node * HID + c] = f2bf(acc > 0.f ? acc : 0.f);
}

// ---------------------------------------------------------------------------
// weight prep: WcT[n][k] = bf16( k<256 ? Wself[k][n] : Wnei[k-256][n] )
// ---------------------------------------------------------------------------
__global__ __launch_bounds__(512) void k_wconv(
    const float* __restrict__ Wself, const float* __restrict__ Wnei,
    unsigned short* __restrict__ WcT) {
  int n = blockIdx.x;   // 0..255
  int k = threadIdx.x;  // 0..511
  float v = (k < HID) ? Wself[k * HID + n] : Wnei[(k - HID) * HID + n];
  WcT[n * 512 + k] = f2bf(v);
}

// ---------------------------------------------------------------------------
// CSR build: histogram -> scan -> fill
// ---------------------------------------------------------------------------
__global__ __launch_bounds__(256) void k_hist(
    const int* __restrict__ dst, int* __restrict__ cnt, int E) {
  int e = blockIdx.x * 256 + threadIdx.x;
  if (e < E) atomicAdd(&cnt[dst[e]], 1);
}

__global__ __launch_bounds__(256) void k_psum(
    const int* __restrict__ cnt, int* __restrict__ psum, int N) {
  __shared__ int ts[256];
  int tid = threadIdx.x;
  int base = blockIdx.x * 1024 + tid * 4;
  int t = 0;
#pragma unroll
  for (int j = 0; j < 4; j++) {
    int i = base + j;
    if (i < N) t += cnt[i];
  }
  ts[tid] = t;
  __syncthreads();
  for (int off = 128; off > 0; off >>= 1) {
    if (tid < off) ts[tid] += ts[tid + off];
    __syncthreads();
  }
  if (tid == 0) psum[blockIdx.x] = ts[0];
}

// parallel exclusive scan of chunk totals (nb <= 128)
__global__ __launch_bounds__(128) void k_scan1(
    const int* __restrict__ psum, int* __restrict__ chunkoff, int nb) {
  __shared__ int ts[128];
  int tid = threadIdx.x;
  int v = (tid < nb) ? psum[tid] : 0;
  ts[tid] = v;
  __syncthreads();
  for (int off = 1; off < 128; off <<= 1) {
    int t = (tid >= off) ? ts[tid - off] : 0;
    __syncthreads();
    ts[tid] += t;
    __syncthreads();
  }
  if (tid < nb) chunkoff[tid] = ts[tid] - v;
}

__global__ __launch_bounds__(256) void k_scan2(
    const int* __restrict__ cnt, const int* __restrict__ chunkoff,
    int* __restrict__ row_start, int* __restrict__ cursor, int N) {
  __shared__ int ts[256];
  int tid = threadIdx.x;
  int base = blockIdx.x * 1024 + tid * 4;
  int v[4];
  int tot = 0;
#pragma unroll
  for (int j = 0; j < 4; j++) {
    int i = base + j;
    v[j] = (i < N) ? cnt[i] : 0;
    tot += v[j];
  }
  ts[tid] = tot;
  __syncthreads();
  for (int off = 1; off < 256; off <<= 1) {
    int t = (tid >= off) ? ts[tid - off] : 0;
    __syncthreads();
    ts[tid] += t;
    __syncthreads();
  }
  int run = chunkoff[blockIdx.x] + ts[tid] - tot;
#pragma unroll
  for (int j = 0; j < 4; j++) {
    int i = base + j;
    if (i < N) { row_start[i] = run; cursor[i] = run; run += v[j]; }
  }
}

__global__ __launch_bounds__(256) void k_fill(
    const int* __restrict__ src, const int* __restrict__ dst,
    int* __restrict__ cursor, int* __restrict__ csr, int E) {
  int e = blockIdx.x * 256 + threadIdx.x;
  if (e >= E) return;
  int d = dst[e];
  int pos = atomicAdd(&cursor[d], 1);
  csr[pos] = src[e];
}

// ---------------------------------------------------------------------------
// k_agg: one wave per node; 2 edges per iteration (each 32-lane half gathers a
// different row at 16 B/lane). fp32 accumulate 8 cols/lane; halves combined
// with shfl_xor(32); lower half writes the bf16 mean row (32 x 16 B = 512 B).
// ---------------------------------------------------------------------------
__global__ __launch_bounds__(256) void k_agg(
    const unsigned short* __restrict__ xb, const int* __restrict__ csr,
    const int* __restrict__ row_start, const int* __restrict__ cnt,
    unsigned short* __restrict__ aggb, int N) {
  int wid = (int)((blockIdx.x * (unsigned)blockDim.x + threadIdx.x) >> 6);
  int lane = threadIdx.x & 63;
  int half = lane >> 5;    // 0 or 1
  int l32 = lane & 31;
  if (wid >= N) return;
  int start = row_start[wid];
  int c = cnt[wid];
  float a[8];
#pragma unroll
  for (int j = 0; j < 8; j++) a[j] = 0.f;

  int i = 0;
  for (; i + 2 <= c; i += 2) {
    int s = csr[start + i + half];
    uint4 v = *(const uint4*)&xb[(size_t)s * HID + l32 * 8];
    a[0] += bflo(v.x); a[1] += bfhi(v.x);
    a[2] += bflo(v.y); a[3] += bfhi(v.y);
    a[4] += bflo(v.z); a[5] += bfhi(v.z);
    a[6] += bflo(v.w); a[7] += bfhi(v.w);
  }
  if ((c & 1) && half == 0) {
    int s = csr[start + c - 1];
    uint4 v = *(const uint4*)&xb[(size_t)s * HID + l32 * 8];
    a[0] += bflo(v.x); a[1] += bfhi(v.x);
    a[2] += bflo(v.y); a[3] += bfhi(v.y);
    a[4] += bflo(v.z); a[5] += bfhi(v.z);
    a[6] += bflo(v.w); a[7] += bfhi(v.w);
  }
  // combine halves
#pragma unroll
  for (int j = 0; j < 8; j++) a[j] += __shfl_xor(a[j], 32);

  if (half == 0) {
    float inv = 1.0f / fmaxf((float)c, 1.0f);
    uint4 o;
    o.x = ((unsigned int)f2bf(a[1] * inv) << 16) | f2bf(a[0] * inv);
    o.y = ((unsigned int)f2bf(a[3] * inv) << 16) | f2bf(a[2] * inv);
    o.z = ((unsigned int)f2bf(a[5] * inv) << 16) | f2bf(a[4] * inv);
    o.w = ((unsigned int)f2bf(a[7] * inv) << 16) | f2bf(a[6] * inv);
    *(uint4*)&aggb[(size_t)wid * HID + l32 * 8] = o;
  }
}

// ---------------------------------------------------------------------------
// k_h: gsum[c] += sum_rows relu( [x|agg] @ WcT^T + bself + bnei )
// MFMA bf16 16x16x32, 128x128 block tile, 4 waves 2x2, 64x64 per wave.
// 1D grid swizzled so the two col-halves of a row-tile are 8 blocks apart
// (same XCD, back-to-back) -> A-tile L2 hit on the second read.
// ---------------------------------------------------------------------------
__global__ __launch_bounds__(256) void k_h(
    const unsigned short* __restrict__ xb, const unsigned short* __restrict__ aggb,
    const unsigned short* __restrict__ WcT, const float* __restrict__ bself,
    const float* __restrict__ bnei, float* __restrict__ gsum, int N, int nfull) {
  __shared__ __align__(16) unsigned short As[128 * ASTR];
  __shared__ __align__(16) unsigned short Bs[128 * ASTR];
  __shared__ float colsum[128];
  int b = blockIdx.x;
  int rt, ch;
  if (b < nfull) {
    rt = (b >> 4) * 8 + (b & 7);
    ch = (b >> 3) & 1;
  } else {
    int rem = b - nfull;
    rt = (nfull >> 1) + (rem >> 1);
    ch = rem & 1;
  }
  int tid = threadIdx.x;
  int rowBase = rt * 128;
  int colBase = ch * 128;
  int lane = tid & 63;
  int wid = tid >> 6;
  int wr = wid >> 1, wc = wid & 1;
  int n16 = lane & 15, quad = lane >> 4;

  if (tid < 128) colsum[tid] = 0.f;

  floatx4 acc[4][4];
#pragma unroll
  for (int i = 0; i < 4; i++)
#pragma unroll
    for (int j = 0; j < 4; j++) acc[i][j] = (floatx4){0.f, 0.f, 0.f, 0.f};

  for (int k0 = 0; k0 < 512; k0 += 32) {
    const unsigned short* abase = (k0 < HID) ? xb : aggb;
    int kc = (k0 < HID) ? k0 : (k0 - HID);
#pragma unroll
    for (int j = 0; j < 2; j++) {
      int idx = tid + j * 256;     // 0..511
      int r = idx >> 2;            // 0..127
      int s = idx & 3;             // 16B segment
      int gr = rowBase + r;
      if (gr >= N) gr = N - 1;
      uint4 va = *(const uint4*)(abase + (size_t)gr * HID + kc + s * 8);
      *(uint4*)(&As[r * ASTR + s * 8]) = va;
      uint4 vb = *(const uint4*)(WcT + (size_t)(colBase + r) * 512 + k0 + s * 8);
      *(uint4*)(&Bs[r * ASTR + s * 8]) = vb;
    }
    __syncthreads();

    short8 af[4], bfr[4];
#pragma unroll
    for (int rt2 = 0; rt2 < 4; rt2++)
      af[rt2] = *(const short8*)&As[(wr * 64 + rt2 * 16 + n16) * ASTR + quad * 8];
#pragma unroll
    for (int ct = 0; ct < 4; ct++)
      bfr[ct] = *(const short8*)&Bs[(wc * 64 + ct * 16 + n16) * ASTR + quad * 8];
#pragma unroll
    for (int rt2 = 0; rt2 < 4; rt2++)
#pragma unroll
      for (int ct = 0; ct < 4; ct++)
        acc[rt2][ct] = __builtin_amdgcn_mfma_f32_16x16x32_bf16(
            af[rt2], bfr[ct], acc[rt2][ct], 0, 0, 0);
    __syncthreads();
  }

  // epilogue: bias + relu + row-masked column sums (C/D: col=lane&15, row=quad*4+reg)
#pragma unroll
  for (int ct = 0; ct < 4; ct++) {
    int lcol = wc * 64 + ct * 16 + n16;
    int gcol = colBase + lcol;
    float bb = bself[gcol] + bnei[gcol];
    float psum = 0.f;
#pragma unroll
    for (int rt2 = 0; rt2 < 4; rt2++) {
#pragma unroll
      for (int r = 0; r < 4; r++) {
        int row = rowBase + wr * 64 + rt2 * 16 + quad * 4 + r;
        float v = acc[rt2][ct][r] + bb;
        v = v > 0.f ? v : 0.f;
        if (row < N) psum += v;
      }
    }
    atomicAdd(&colsum[lcol], psum);
  }
  __syncthreads();
  if (tid < 128) atomicAdd(&gsum[colBase + tid], colsum[tid]);
}

// ---------------------------------------------------------------------------
// k_out: out = (gsum / N) @ W_out + b_out   single block, 256 threads
// ---------------------------------------------------------------------------
__global__ __launch_bounds__(HID) void k_out(
    const float* __restrict__ gsum, const float* __restrict__ Wout,
    const float* __restrict__ bout, float* __restrict__ out, float invN) {
  __shared__ float g[HID];
  int c = threadIdx.x;
  g[c] = gsum[c] * invN;
  __syncthreads();
  float acc = bout[c];
#pragma unroll 8
  for (int k = 0; k < HID; k++) acc += g[k] * Wout[k * HID + c];
  out[c] = acc;
}

extern "C" void kernel_launch(void* const* d_in, const int* in_sizes, int n_in,
                              void* d_out, int out_size, void* d_ws, size_t ws_size,
                              hipStream_t stream) {
  const float* ns    = (const float*)d_in[0];
  const float* Win   = (const float*)d_in[1];
  const float* bin   = (const float*)d_in[2];
  const float* Wself = (const float*)d_in[3];
  const float* bself = (const float*)d_in[4];
  const float* Wnei  = (const float*)d_in[5];
  const float* bnei  = (const float*)d_in[6];
  const float* Wout  = (const float*)d_in[7];
  const float* bout  = (const float*)d_in[8];
  const int*   eidx  = (const int*)d_in[9];

  int N = in_sizes[0] / IND;
  int E = in_sizes[9] / 2;
  const int* src = eidx;
  const int* dst = eidx + E;

  // ws layout: xb[N*H] bf16 | aggb[N*H] bf16 | WcT[256*512] bf16 | csr[E] i |
  //            cnt[N] i | row_start[N] i | cursor[N] i | chunkoff[128] i | gsum[H] f
  unsigned short* xb   = (unsigned short*)d_ws;
  unsigned short* aggb = xb + (size_t)N * HID;
  unsigned short* WcT  = aggb + (size_t)N * HID;
  int* csr       = (int*)(WcT + 256 * 512);
  int* cnt       = csr + E;
  int* row_start = cnt + N;
  int* cursor    = row_start + N;
  int* chunkoff  = cursor + N;
  float* gsum    = (float*)(chunkoff + 128);

  hipMemsetAsync(cnt, 0, (size_t)N * sizeof(int), stream);
  hipMemsetAsync(gsum, 0, HID * sizeof(float), stream);

  k_linear_in<<<N, HID, 0, stream>>>(ns, Win, bin, xb, N);
  k_wconv<<<256, 512, 0, stream>>>(Wself, Wnei, WcT);

  int egrid = (E + 255) / 256;
  k_hist<<<egrid, 256, 0, stream>>>(dst, cnt, E);

  int nb = (N + 1023) / 1024;
  k_psum<<<nb, 256, 0, stream>>>(cnt, cursor, N);
  k_scan1<<<1, 128, 0, stream>>>(cursor, chunkoff, nb);
  k_scan2<<<nb, 256, 0, stream>>>(cnt, chunkoff, row_start, cursor, N);

  k_fill<<<egrid, 256, 0, stream>>>(src, dst, cursor, csr, E);

  int agrid = (N + 3) / 4;
  k_agg<<<agrid, 256, 0, stream>>>(xb, csr, row_start, cnt, aggb, N);

  int ntiles = (N + 127) / 128;          // 782
  int nblocks = ntiles * 2;              // 1564
  int nfull = (nblocks / 16) * 16;       // full 16-block swizzle groups
  k_h<<<nblocks, 256, 0, stream>>>(xb, aggb, WcT, bself, bnei, gsum, N, nfull);

  k_out<<<1, HID, 0, stream>>>(gsum, Wout, bout, (float*)d_out, 1.0f / (float)N);
}

// Round 5
// 418.172 us; speedup vs baseline: 14.5223x; 1.3043x over previous
//
#include <hip/hip_runtime.h>
#include <hip/hip_bf16.h>

#define HID 256
#define IND 21
#define ASTR 40      // LDS row stride in bf16 elems (80 B): 2-way bank conflicts only
#define PB 3200      // edges per block in k_part
#define MAXB 512     // max buckets (N <= 131072)

typedef short short8 __attribute__((ext_vector_type(8)));
typedef float floatx4 __attribute__((ext_vector_type(4)));

__device__ inline float bflo(unsigned int u) {
  union { unsigned int i; float f; } c; c.i = u << 16; return c.f;
}
__device__ inline float bfhi(unsigned int u) {
  union { unsigned int i; float f; } c; c.i = u & 0xffff0000u; return c.f;
}
__device__ inline unsigned short f2bf(float f) {
  __hip_bfloat16 h = __float2bfloat16(f);  // RNE
  union { __hip_bfloat16 h; unsigned short u; } c;
  c.h = h;
  return c.u;
}

// ---------------------------------------------------------------------------
// k1: xb = bf16(relu(ns @ W_in + b_in)). 8 nodes/block; each thread owns one
// output column and keeps its 21 W_in values in registers across the 8 nodes.
// ---------------------------------------------------------------------------
__global__ __launch_bounds__(256) void k_linear_in(
    const float* __restrict__ ns, const float* __restrict__ Win,
    const float* __restrict__ bin, unsigned short* __restrict__ xb, int N) {
  __shared__ float s[8][IND];
  int nb = blockIdx.x * 8;
  int tid = threadIdx.x;
  if (tid < 8 * IND) {
    int idx = nb * IND + tid;
    s[tid / IND][tid % IND] = (idx < N * IND) ? ns[idx] : 0.f;
  }
  float w[IND];
#pragma unroll
  for (int k = 0; k < IND; k++) w[k] = Win[k * HID + tid];
  float b = bin[tid];
  __syncthreads();
#pragma unroll
  for (int j = 0; j < 8; j++) {
    int node = nb + j;
    if (node >= N) break;
    float acc = b;
#pragma unroll
    for (int k = 0; k < IND; k++) acc += s[j][k] * w[k];
    xb[(size_t)node * HID + tid] = f2bf(acc > 0.f ? acc : 0.f);
  }
}

// ---------------------------------------------------------------------------
// weight prep: WcT[n][k] = bf16( k<256 ? Wself[k][n] : Wnei[k-256][n] )
// ---------------------------------------------------------------------------
__global__ __launch_bounds__(512) void k_wconv(
    const float* __restrict__ Wself, const float* __restrict__ Wnei,
    unsigned short* __restrict__ WcT) {
  int n = blockIdx.x;
  int k = threadIdx.x;
  float v = (k < HID) ? Wself[k * HID + n] : Wnei[(k - HID) * HID + n];
  WcT[n * 512 + k] = f2bf(v);
}

// ---------------------------------------------------------------------------
// CSR build: histogram -> scan (row_start + bucket bases) -> partition -> fill
// ---------------------------------------------------------------------------
__global__ __launch_bounds__(256) void k_hist(
    const int* __restrict__ dst, int* __restrict__ cnt, int E) {
  int e = blockIdx.x * 256 + threadIdx.x;
  if (e < E) atomicAdd(&cnt[dst[e]], 1);
}

__global__ __launch_bounds__(256) void k_psum(
    const int* __restrict__ cnt, int* __restrict__ psum, int N) {
  __shared__ int ts[256];
  int tid = threadIdx.x;
  int base = blockIdx.x * 1024 + tid * 4;
  int t = 0;
#pragma unroll
  for (int j = 0; j < 4; j++) {
    int i = base + j;
    if (i < N) t += cnt[i];
  }
  ts[tid] = t;
  __syncthreads();
  for (int off = 128; off > 0; off >>= 1) {
    if (tid < off) ts[tid] += ts[tid + off];
    __syncthreads();
  }
  if (tid == 0) psum[blockIdx.x] = ts[0];
}

__global__ __launch_bounds__(128) void k_scan1(
    const int* __restrict__ psum, int* __restrict__ chunkoff, int nb) {
  __shared__ int ts[128];
  int tid = threadIdx.x;
  int v = (tid < nb) ? psum[tid] : 0;
  ts[tid] = v;
  __syncthreads();
  for (int off = 1; off < 128; off <<= 1) {
    int t = (tid >= off) ? ts[tid - off] : 0;
    __syncthreads();
    ts[tid] += t;
    __syncthreads();
  }
  if (tid < nb) chunkoff[tid] = ts[tid] - v;
}

// row_start + bucket cursor init (bcur[b] = row_start[b<<8])
__global__ __launch_bounds__(256) void k_scan2(
    const int* __restrict__ cnt, const int* __restrict__ chunkoff,
    int* __restrict__ row_start, int* __restrict__ bcur, int N) {
  __shared__ int ts[256];
  int tid = threadIdx.x;
  int base = blockIdx.x * 1024 + tid * 4;
  int v[4];
  int tot = 0;
#pragma unroll
  for (int j = 0; j < 4; j++) {
    int i = base + j;
    v[j] = (i < N) ? cnt[i] : 0;
    tot += v[j];
  }
  ts[tid] = tot;
  __syncthreads();
  for (int off = 1; off < 256; off <<= 1) {
    int t = (tid >= off) ? ts[tid - off] : 0;
    __syncthreads();
    ts[tid] += t;
    __syncthreads();
  }
  int run = chunkoff[blockIdx.x] + ts[tid] - tot;
#pragma unroll
  for (int j = 0; j < 4; j++) {
    int i = base + j;
    if (i < N) {
      row_start[i] = run;
      if ((i & 255) == 0) bcur[i >> 8] = run;
      run += v[j];
    }
  }
}

// pass 1: partition edges into per-bucket regions of ebuf (bucket = dst>>8).
// Block-level LDS histogram -> one global reservation per (block,bucket) ->
// contiguous-ish 8B writes. Kills write amplification.
__global__ __launch_bounds__(256) void k_part(
    const int* __restrict__ src, const int* __restrict__ dst,
    int* __restrict__ bcur, uint2* __restrict__ ebuf, int E, int nb2) {
  __shared__ int lh[MAXB];
  __shared__ uint2 est[PB];
  int tid = threadIdx.x;
  int e0 = blockIdx.x * PB;
  for (int b = tid; b < nb2; b += 256) lh[b] = 0;
  __syncthreads();
  int cnt = min(PB, E - e0);
  for (int i = tid; i < cnt; i += 256) {
    int s = src[e0 + i];
    int d = dst[e0 + i];
    est[i] = make_uint2((unsigned)s, (unsigned)d);
    atomicAdd(&lh[d >> 8], 1);
  }
  __syncthreads();
  for (int b = tid; b < nb2; b += 256) {
    int c = lh[b];
    lh[b] = (c > 0) ? atomicAdd(&bcur[b], c) : 0;
  }
  __syncthreads();
  for (int i = tid; i < cnt; i += 256) {
    uint2 e = est[i];
    int pos = atomicAdd(&lh[e.y >> 8], 1);
    ebuf[pos] = e;
  }
}

// pass 2: one block per bucket; LDS per-node cursors; csr writes land in a
// ~16KB cache-resident window.
__global__ __launch_bounds__(256) void k_fill2(
    const uint2* __restrict__ ebuf, const int* __restrict__ row_start,
    int* __restrict__ csr, int N, int E, int nb2) {
  __shared__ int lcur[256];
  int b = blockIdx.x;
  int tid = threadIdx.x;
  int node0 = b << 8;
  int node = node0 + tid;
  lcur[tid] = (node < N) ? row_start[node] : 0;
  int start = row_start[node0];
  int end = (node0 + 256 >= N) ? E : row_start[node0 + 256];
  __syncthreads();
  for (int i = start + tid; i < end; i += 256) {
    uint2 e = ebuf[i];
    int pos = atomicAdd(&lcur[e.y & 255], 1);
    csr[pos] = (int)e.x;
  }
}

// ---------------------------------------------------------------------------
// k_agg: one wave per node; 2 edges per iteration (each 32-lane half gathers a
// different row at 16 B/lane). fp32 accumulate; halves combined via shfl_xor.
// ---------------------------------------------------------------------------
__global__ __launch_bounds__(256) void k_agg(
    const unsigned short* __restrict__ xb, const int* __restrict__ csr,
    const int* __restrict__ row_start, const int* __restrict__ cnt,
    unsigned short* __restrict__ aggb, int N) {
  int wid = (int)((blockIdx.x * (unsigned)blockDim.x + threadIdx.x) >> 6);
  int lane = threadIdx.x & 63;
  int half = lane >> 5;
  int l32 = lane & 31;
  if (wid >= N) return;
  int start = row_start[wid];
  int c = cnt[wid];
  float a[8];
#pragma unroll
  for (int j = 0; j < 8; j++) a[j] = 0.f;

  int i = 0;
  for (; i + 2 <= c; i += 2) {
    int s = csr[start + i + half];
    uint4 v = *(const uint4*)&xb[(size_t)s * HID + l32 * 8];
    a[0] += bflo(v.x); a[1] += bfhi(v.x);
    a[2] += bflo(v.y); a[3] += bfhi(v.y);
    a[4] += bflo(v.z); a[5] += bfhi(v.z);
    a[6] += bflo(v.w); a[7] += bfhi(v.w);
  }
  if ((c & 1) && half == 0) {
    int s = csr[start + c - 1];
    uint4 v = *(const uint4*)&xb[(size_t)s * HID + l32 * 8];
    a[0] += bflo(v.x); a[1] += bfhi(v.x);
    a[2] += bflo(v.y); a[3] += bfhi(v.y);
    a[4] += bflo(v.z); a[5] += bfhi(v.z);
    a[6] += bflo(v.w); a[7] += bfhi(v.w);
  }
#pragma unroll
  for (int j = 0; j < 8; j++) a[j] += __shfl_xor(a[j], 32);

  if (half == 0) {
    float inv = 1.0f / fmaxf((float)c, 1.0f);
    uint4 o;
    o.x = ((unsigned int)f2bf(a[1] * inv) << 16) | f2bf(a[0] * inv);
    o.y = ((unsigned int)f2bf(a[3] * inv) << 16) | f2bf(a[2] * inv);
    o.z = ((unsigned int)f2bf(a[5] * inv) << 16) | f2bf(a[4] * inv);
    o.w = ((unsigned int)f2bf(a[7] * inv) << 16) | f2bf(a[6] * inv);
    *(uint4*)&aggb[(size_t)wid * HID + l32 * 8] = o;
  }
}

// ---------------------------------------------------------------------------
// k_h: gsum[c] += sum_rows relu( [x|agg] @ WcT^T + bself + bnei )
// MFMA bf16 16x16x32, 128x128 block tile, 4 waves 2x2, 64x64 per wave.
// 1D grid swizzled so the two col-halves of a row-tile are 8 blocks apart.
// ---------------------------------------------------------------------------
__global__ __launch_bounds__(256) void k_h(
    const unsigned short* __restrict__ xb, const unsigned short* __restrict__ aggb,
    const unsigned short* __restrict__ WcT, const float* __restrict__ bself,
    const float* __restrict__ bnei, float* __restrict__ gsum, int N, int nfull) {
  __shared__ __align__(16) unsigned short As[128 * ASTR];
  __shared__ __align__(16) unsigned short Bs[128 * ASTR];
  __shared__ float colsum[128];
  int b = blockIdx.x;
  int rt, ch;
  if (b < nfull) {
    rt = (b >> 4) * 8 + (b & 7);
    ch = (b >> 3) & 1;
  } else {
    int rem = b - nfull;
    rt = (nfull >> 1) + (rem >> 1);
    ch = rem & 1;
  }
  int tid = threadIdx.x;
  int rowBase = rt * 128;
  int colBase = ch * 128;
  int lane = tid & 63;
  int wid = tid >> 6;
  int wr = wid >> 1, wc = wid & 1;
  int n16 = lane & 15, quad = lane >> 4;

  if (tid < 128) colsum[tid] = 0.f;

  floatx4 acc[4][4];
#pragma unroll
  for (int i = 0; i < 4; i++)
#pragma unroll
    for (int j = 0; j < 4; j++) acc[i][j] = (floatx4){0.f, 0.f, 0.f, 0.f};

  for (int k0 = 0; k0 < 512; k0 += 32) {
    const unsigned short* abase = (k0 < HID) ? xb : aggb;
    int kc = (k0 < HID) ? k0 : (k0 - HID);
#pragma unroll
    for (int j = 0; j < 2; j++) {
      int idx = tid + j * 256;
      int r = idx >> 2;
      int s = idx & 3;
      int gr = rowBase + r;
      if (gr >= N) gr = N - 1;
      uint4 va = *(const uint4*)(abase + (size_t)gr * HID + kc + s * 8);
      *(uint4*)(&As[r * ASTR + s * 8]) = va;
      uint4 vb = *(const uint4*)(WcT + (size_t)(colBase + r) * 512 + k0 + s * 8);
      *(uint4*)(&Bs[r * ASTR + s * 8]) = vb;
    }
    __syncthreads();

    short8 af[4], bfr[4];
#pragma unroll
    for (int rt2 = 0; rt2 < 4; rt2++)
      af[rt2] = *(const short8*)&As[(wr * 64 + rt2 * 16 + n16) * ASTR + quad * 8];
#pragma unroll
    for (int ct = 0; ct < 4; ct++)
      bfr[ct] = *(const short8*)&Bs[(wc * 64 + ct * 16 + n16) * ASTR + quad * 8];
#pragma unroll
    for (int rt2 = 0; rt2 < 4; rt2++)
#pragma unroll
      for (int ct = 0; ct < 4; ct++)
        acc[rt2][ct] = __builtin_amdgcn_mfma_f32_16x16x32_bf16(
            af[rt2], bfr[ct], acc[rt2][ct], 0, 0, 0);
    __syncthreads();
  }

#pragma unroll
  for (int ct = 0; ct < 4; ct++) {
    int lcol = wc * 64 + ct * 16 + n16;
    int gcol = colBase + lcol;
    float bb = bself[gcol] + bnei[gcol];
    float psum = 0.f;
#pragma unroll
    for (int rt2 = 0; rt2 < 4; rt2++) {
#pragma unroll
      for (int r = 0; r < 4; r++) {
        int row = rowBase + wr * 64 + rt2 * 16 + quad * 4 + r;
        float v = acc[rt2][ct][r] + bb;
        v = v > 0.f ? v : 0.f;
        if (row < N) psum += v;
      }
    }
    atomicAdd(&colsum[lcol], psum);
  }
  __syncthreads();
  if (tid < 128) atomicAdd(&gsum[colBase + tid], colsum[tid]);
}

// ---------------------------------------------------------------------------
// k_out: out = (gsum / N) @ W_out + b_out   single block, 256 threads
// ---------------------------------------------------------------------------
__global__ __launch_bounds__(HID) void k_out(
    const float* __restrict__ gsum, const float* __restrict__ Wout,
    const float* __restrict__ bout, float* __restrict__ out, float invN) {
  __shared__ float g[HID];
  int c = threadIdx.x;
  g[c] = gsum[c] * invN;
  __syncthreads();
  float acc = bout[c];
#pragma unroll 8
  for (int k = 0; k < HID; k++) acc += g[k] * Wout[k * HID + c];
  out[c] = acc;
}

extern "C" void kernel_launch(void* const* d_in, const int* in_sizes, int n_in,
                              void* d_out, int out_size, void* d_ws, size_t ws_size,
                              hipStream_t stream) {
  const float* ns    = (const float*)d_in[0];
  const float* Win   = (const float*)d_in[1];
  const float* bin   = (const float*)d_in[2];
  const float* Wself = (const float*)d_in[3];
  const float* bself = (const float*)d_in[4];
  const float* Wnei  = (const float*)d_in[5];
  const float* bnei  = (const float*)d_in[6];
  const float* Wout  = (const float*)d_in[7];
  const float* bout  = (const float*)d_in[8];
  const int*   eidx  = (const int*)d_in[9];

  int N = in_sizes[0] / IND;
  int E = in_sizes[9] / 2;
  const int* src = eidx;
  const int* dst = eidx + E;
  int nb2 = (N + 255) >> 8;   // buckets of 256 nodes

  // ws layout: xb[N*H] bf16 | aggb[N*H] bf16 | WcT[256*512] bf16 | csr[E] i |
  //   ebuf[E] uint2 | cnt[N] i | row_start[N] i | psum[128] i | chunkoff[128] i |
  //   bcur[MAXB] i | gsum[H] f
  unsigned short* xb   = (unsigned short*)d_ws;
  unsigned short* aggb = xb + (size_t)N * HID;
  unsigned short* WcT  = aggb + (size_t)N * HID;
  int* csr       = (int*)(WcT + 256 * 512);
  uint2* ebuf    = (uint2*)(csr + E);
  int* cnt       = (int*)(ebuf + E);
  int* row_start = cnt + N;
  int* psum      = row_start + N;
  int* chunkoff  = psum + 128;
  int* bcur      = chunkoff + 128;
  float* gsum    = (float*)(bcur + MAXB);

  hipMemsetAsync(cnt, 0, (size_t)N * sizeof(int), stream);
  hipMemsetAsync(gsum, 0, HID * sizeof(float), stream);

  k_linear_in<<<(N + 7) / 8, 256, 0, stream>>>(ns, Win, bin, xb, N);
  k_wconv<<<256, 512, 0, stream>>>(Wself, Wnei, WcT);

  int egrid = (E + 255) / 256;
  k_hist<<<egrid, 256, 0, stream>>>(dst, cnt, E);

  int nb = (N + 1023) / 1024;
  k_psum<<<nb, 256, 0, stream>>>(cnt, psum, N);
  k_scan1<<<1, 128, 0, stream>>>(psum, chunkoff, nb);
  k_scan2<<<nb, 256, 0, stream>>>(cnt, chunkoff, row_start, bcur, N);

  k_part<<<(E + PB - 1) / PB, 256, 0, stream>>>(src, dst, bcur, ebuf, E, nb2);
  k_fill2<<<nb2, 256, 0, stream>>>(ebuf, row_start, csr, N, E, nb2);

  int agrid = (N + 3) / 4;
  k_agg<<<agrid, 256, 0, stream>>>(xb, csr, row_start, cnt, aggb, N);

  int ntiles = (N + 127) / 128;
  int nblocks = ntiles * 2;
  int nfull = (nblocks / 16) * 16;
  k_h<<<nblocks, 256, 0, stream>>>(xb, aggb, WcT, bself, bnei, gsum, N, nfull);

  k_out<<<1, HID, 0, stream>>>(gsum, Wout, bout, (float*)d_out, 1.0f / (float)N);
}

// Round 6
// 375.045 us; speedup vs baseline: 16.1922x; 1.1150x over previous
//
#include <hip/hip_runtime.h>
#include <hip/hip_bf16.h>

#define HID 256
#define IND 21
#define ASTR 40      // LDS row stride in bf16 elems (80 B): 2-way bank conflicts only
#define PB 3200      // edges per block in k_part / k_bhist
#define MAXB 512     // max buckets (N <= 131072)

typedef short short8 __attribute__((ext_vector_type(8)));
typedef float floatx4 __attribute__((ext_vector_type(4)));

__device__ inline float bflo(unsigned int u) {
  union { unsigned int i; float f; } c; c.i = u << 16; return c.f;
}
__device__ inline float bfhi(unsigned int u) {
  union { unsigned int i; float f; } c; c.i = u & 0xffff0000u; return c.f;
}
__device__ inline unsigned short f2bf(float f) {
  __hip_bfloat16 h = __float2bfloat16(f);  // RNE
  union { __hip_bfloat16 h; unsigned short u; } c;
  c.h = h;
  return c.u;
}

// ---------------------------------------------------------------------------
// k1: xb = bf16(relu(ns @ W_in + b_in)). 8 nodes/block; each thread owns one
// output column, W_in column kept in registers across the 8 nodes.
// ---------------------------------------------------------------------------
__global__ __launch_bounds__(256) void k_linear_in(
    const float* __restrict__ ns, const float* __restrict__ Win,
    const float* __restrict__ bin, unsigned short* __restrict__ xb, int N) {
  __shared__ float s[8][IND];
  int nb = blockIdx.x * 8;
  int tid = threadIdx.x;
  if (tid < 8 * IND) {
    int idx = nb * IND + tid;
    s[tid / IND][tid % IND] = (idx < N * IND) ? ns[idx] : 0.f;
  }
  float w[IND];
#pragma unroll
  for (int k = 0; k < IND; k++) w[k] = Win[k * HID + tid];
  float b = bin[tid];
  __syncthreads();
#pragma unroll
  for (int j = 0; j < 8; j++) {
    int node = nb + j;
    if (node >= N) break;
    float acc = b;
#pragma unroll
    for (int k = 0; k < IND; k++) acc += s[j][k] * w[k];
    xb[(size_t)node * HID + tid] = f2bf(acc > 0.f ? acc : 0.f);
  }
}

// ---------------------------------------------------------------------------
// weight prep: WcT[n][k] = bf16( k<256 ? Wself[k][n] : Wnei[k-256][n] )
// ---------------------------------------------------------------------------
__global__ __launch_bounds__(512) void k_wconv(
    const float* __restrict__ Wself, const float* __restrict__ Wnei,
    unsigned short* __restrict__ WcT) {
  int n = blockIdx.x;
  int k = threadIdx.x;
  float v = (k < HID) ? Wself[k * HID + n] : Wnei[(k - HID) * HID + n];
  WcT[n * 512 + k] = f2bf(v);
}

// ---------------------------------------------------------------------------
// CSR build: bucket hist -> bucket scan -> partition -> per-bucket scan+fill
// bucket = dst >> 8 (256 nodes per bucket)
// ---------------------------------------------------------------------------
__global__ __launch_bounds__(256) void k_bhist(
    const int* __restrict__ dst, int* __restrict__ bcnt, int E, int nb2) {
  __shared__ int lh[MAXB];
  int tid = threadIdx.x;
  int e0 = blockIdx.x * PB;
  for (int b = tid; b < nb2; b += 256) lh[b] = 0;
  __syncthreads();
  int c = min(PB, E - e0);
  for (int i = tid; i < c; i += 256) atomicAdd(&lh[dst[e0 + i] >> 8], 1);
  __syncthreads();
  for (int b = tid; b < nb2; b += 256)
    if (lh[b]) atomicAdd(&bcnt[b], lh[b]);
}

// single block: exclusive scan of bucket counts -> bbase, bcur; sentinels
__global__ __launch_bounds__(512) void k_bscan(
    const int* __restrict__ bcnt, int* __restrict__ bbase, int* __restrict__ bcur,
    int* __restrict__ row_start, int E, int N, int nb2) {
  __shared__ int ts[512];
  int tid = threadIdx.x;
  int v = (tid < nb2) ? bcnt[tid] : 0;
  ts[tid] = v;
  __syncthreads();
  for (int off = 1; off < 512; off <<= 1) {
    int t = (tid >= off) ? ts[tid - off] : 0;
    __syncthreads();
    ts[tid] += t;
    __syncthreads();
  }
  if (tid < nb2) { bbase[tid] = ts[tid] - v; bcur[tid] = ts[tid] - v; }
  if (tid == 0) { bbase[nb2] = E; row_start[N] = E; }
}

// partition edges into per-bucket regions of ebuf. Block-level LDS histogram
// -> one global reservation per (block,bucket) -> dense 8B writes.
__global__ __launch_bounds__(256) void k_part(
    const int* __restrict__ src, const int* __restrict__ dst,
    int* __restrict__ bcur, uint2* __restrict__ ebuf, int E, int nb2) {
  __shared__ int lh[MAXB];
  __shared__ uint2 est[PB];
  int tid = threadIdx.x;
  int e0 = blockIdx.x * PB;
  for (int b = tid; b < nb2; b += 256) lh[b] = 0;
  __syncthreads();
  int cnt = min(PB, E - e0);
  for (int i = tid; i < cnt; i += 256) {
    int s = src[e0 + i];
    int d = dst[e0 + i];
    est[i] = make_uint2((unsigned)s, (unsigned)d);
    atomicAdd(&lh[d >> 8], 1);
  }
  __syncthreads();
  for (int b = tid; b < nb2; b += 256) {
    int c = lh[b];
    lh[b] = (c > 0) ? atomicAdd(&bcur[b], c) : 0;
  }
  __syncthreads();
  for (int i = tid; i < cnt; i += 256) {
    uint2 e = est[i];
    int pos = atomicAdd(&lh[e.y >> 8], 1);
    ebuf[pos] = e;
  }
}

// one block per bucket: LDS count + scan -> row_start; LDS cursors -> csr.
// csr writes land in a ~16KB cache-resident window (no write amplification).
__global__ __launch_bounds__(256) void k_fill2(
    const uint2* __restrict__ ebuf, const int* __restrict__ bbase,
    int* __restrict__ row_start, int* __restrict__ csr, int N) {
  __shared__ int lcnt[256];
  __shared__ int lcur[256];
  __shared__ int ts[256];
  int b = blockIdx.x;
  int tid = threadIdx.x;
  int start = bbase[b], end = bbase[b + 1];
  lcnt[tid] = 0;
  __syncthreads();
  for (int i = start + tid; i < end; i += 256)
    atomicAdd(&lcnt[ebuf[i].y & 255], 1);
  __syncthreads();
  int v = lcnt[tid];
  ts[tid] = v;
  __syncthreads();
  for (int off = 1; off < 256; off <<= 1) {
    int t = (tid >= off) ? ts[tid - off] : 0;
    __syncthreads();
    ts[tid] += t;
    __syncthreads();
  }
  int excl = start + ts[tid] - v;
  int node = (b << 8) + tid;
  if (node < N) row_start[node] = excl;
  lcur[tid] = excl;
  __syncthreads();
  for (int i = start + tid; i < end; i += 256) {
    uint2 e = ebuf[i];
    int pos = atomicAdd(&lcur[e.y & 255], 1);
    csr[pos] = (int)e.x;
  }
}

// ---------------------------------------------------------------------------
// k_agg: one wave per node; 4 edges per iteration (2 independent row loads in
// flight per 32-lane half, separate accumulator banks). fp32 accumulate;
// halves combined via shfl_xor; bf16 mean written by lower half.
// ---------------------------------------------------------------------------
__global__ __launch_bounds__(256) void k_agg(
    const unsigned short* __restrict__ xb, const int* __restrict__ csr,
    const int* __restrict__ row_start, unsigned short* __restrict__ aggb, int N) {
  int wid = (int)((blockIdx.x * (unsigned)blockDim.x + threadIdx.x) >> 6);
  int lane = threadIdx.x & 63;
  int half = lane >> 5;
  int l32 = lane & 31;
  if (wid >= N) return;
  int start = row_start[wid];
  int end = row_start[wid + 1];
  int c = end - start;
  float a[8], b2[8];
#pragma unroll
  for (int j = 0; j < 8; j++) { a[j] = 0.f; b2[j] = 0.f; }

  int i = 0;
  for (; i + 4 <= c; i += 4) {
    int s0 = csr[start + i + half];
    int s1 = csr[start + i + 2 + half];
    uint4 v0 = *(const uint4*)&xb[(size_t)s0 * HID + l32 * 8];
    uint4 v1 = *(const uint4*)&xb[(size_t)s1 * HID + l32 * 8];
    a[0] += bflo(v0.x); a[1] += bfhi(v0.x);
    a[2] += bflo(v0.y); a[3] += bfhi(v0.y);
    a[4] += bflo(v0.z); a[5] += bfhi(v0.z);
    a[6] += bflo(v0.w); a[7] += bfhi(v0.w);
    b2[0] += bflo(v1.x); b2[1] += bfhi(v1.x);
    b2[2] += bflo(v1.y); b2[3] += bfhi(v1.y);
    b2[4] += bflo(v1.z); b2[5] += bfhi(v1.z);
    b2[6] += bflo(v1.w); b2[7] += bfhi(v1.w);
  }
  if (i + 2 <= c) {
    int s0 = csr[start + i + half];
    uint4 v0 = *(const uint4*)&xb[(size_t)s0 * HID + l32 * 8];
    a[0] += bflo(v0.x); a[1] += bfhi(v0.x);
    a[2] += bflo(v0.y); a[3] += bfhi(v0.y);
    a[4] += bflo(v0.z); a[5] += bfhi(v0.z);
    a[6] += bflo(v0.w); a[7] += bfhi(v0.w);
    i += 2;
  }
  if ((c & 1) && half == 0) {
    int s0 = csr[start + c - 1];
    uint4 v0 = *(const uint4*)&xb[(size_t)s0 * HID + l32 * 8];
    a[0] += bflo(v0.x); a[1] += bfhi(v0.x);
    a[2] += bflo(v0.y); a[3] += bfhi(v0.y);
    a[4] += bflo(v0.z); a[5] += bfhi(v0.z);
    a[6] += bflo(v0.w); a[7] += bfhi(v0.w);
  }
#pragma unroll
  for (int j = 0; j < 8; j++) a[j] += b2[j];
#pragma unroll
  for (int j = 0; j < 8; j++) a[j] += __shfl_xor(a[j], 32);

  if (half == 0) {
    float inv = 1.0f / fmaxf((float)c, 1.0f);
    uint4 o;
    o.x = ((unsigned int)f2bf(a[1] * inv) << 16) | f2bf(a[0] * inv);
    o.y = ((unsigned int)f2bf(a[3] * inv) << 16) | f2bf(a[2] * inv);
    o.z = ((unsigned int)f2bf(a[5] * inv) << 16) | f2bf(a[4] * inv);
    o.w = ((unsigned int)f2bf(a[7] * inv) << 16) | f2bf(a[6] * inv);
    *(uint4*)&aggb[(size_t)wid * HID + l32 * 8] = o;
  }
}

// ---------------------------------------------------------------------------
// k_h: gsum[c] += sum_rows relu( [x|agg] @ WcT^T + bself + bnei )
// 128 rows x 256 cols per block (full output width -> A staged exactly once).
// 4 waves 2x2; wave = 64 rows x 128 cols; B frags loaded just-in-time to
// bound VGPRs (~160). MFMA bf16 16x16x32, K=512 in chunks of 32.
// ---------------------------------------------------------------------------
__global__ __launch_bounds__(256, 2) void k_h(
    const unsigned short* __restrict__ xb, const unsigned short* __restrict__ aggb,
    const unsigned short* __restrict__ WcT, const float* __restrict__ bself,
    const float* __restrict__ bnei, float* __restrict__ gsum, int N) {
  __shared__ __align__(16) unsigned short As[128 * ASTR];
  __shared__ __align__(16) unsigned short Bs[256 * ASTR];
  __shared__ float colsum[256];
  int tid = threadIdx.x;
  int rowBase = blockIdx.x * 128;
  int lane = tid & 63;
  int wid = tid >> 6;
  int wr = wid >> 1, wc = wid & 1;
  int n16 = lane & 15, quad = lane >> 4;

  colsum[tid] = 0.f;

  floatx4 acc[4][8];
#pragma unroll
  for (int i = 0; i < 4; i++)
#pragma unroll
    for (int j = 0; j < 8; j++) acc[i][j] = (floatx4){0.f, 0.f, 0.f, 0.f};

  for (int k0 = 0; k0 < 512; k0 += 32) {
    const unsigned short* abase = (k0 < HID) ? xb : aggb;
    int kc = (k0 < HID) ? k0 : (k0 - HID);
    // stage A: 128 rows x 32 k = 512 uint4 -> 2/thread
#pragma unroll
    for (int j = 0; j < 2; j++) {
      int idx = tid + j * 256;
      int r = idx >> 2;
      int s = idx & 3;
      int gr = rowBase + r;
      if (gr >= N) gr = N - 1;
      uint4 va = *(const uint4*)(abase + (size_t)gr * HID + kc + s * 8);
      *(uint4*)(&As[r * ASTR + s * 8]) = va;
    }
    // stage B: 256 cols x 32 k = 1024 uint4 -> 4/thread
#pragma unroll
    for (int j = 0; j < 4; j++) {
      int idx = tid + j * 256;
      int r = idx >> 2;
      int s = idx & 3;
      uint4 vb = *(const uint4*)(WcT + (size_t)r * 512 + k0 + s * 8);
      *(uint4*)(&Bs[r * ASTR + s * 8]) = vb;
    }
    __syncthreads();

    short8 af[4];
#pragma unroll
    for (int rt = 0; rt < 4; rt++)
      af[rt] = *(const short8*)&As[(wr * 64 + rt * 16 + n16) * ASTR + quad * 8];
#pragma unroll
    for (int ct = 0; ct < 8; ct++) {
      short8 bf = *(const short8*)&Bs[(wc * 128 + ct * 16 + n16) * ASTR + quad * 8];
#pragma unroll
      for (int rt = 0; rt < 4; rt++)
        acc[rt][ct] = __builtin_amdgcn_mfma_f32_16x16x32_bf16(
            af[rt], bf, acc[rt][ct], 0, 0, 0);
    }
    __syncthreads();
  }

  // epilogue: bias + relu + row-masked column sums (C/D: col=lane&15, row=quad*4+reg)
#pragma unroll
  for (int ct = 0; ct < 8; ct++) {
    int gcol = wc * 128 + ct * 16 + n16;
    float bb = bself[gcol] + bnei[gcol];
    float psum = 0.f;
#pragma unroll
    for (int rt = 0; rt < 4; rt++) {
#pragma unroll
      for (int r = 0; r < 4; r++) {
        int row = rowBase + wr * 64 + rt * 16 + quad * 4 + r;
        float v = acc[rt][ct][r] + bb;
        v = v > 0.f ? v : 0.f;
        if (row < N) psum += v;
      }
    }
    atomicAdd(&colsum[gcol], psum);
  }
  __syncthreads();
  atomicAdd(&gsum[tid], colsum[tid]);
}

// ---------------------------------------------------------------------------
// k_out: out = (gsum / N) @ W_out + b_out   single block, 256 threads
// ---------------------------------------------------------------------------
__global__ __launch_bounds__(HID) void k_out(
    const float* __restrict__ gsum, const float* __restrict__ Wout,
    const float* __restrict__ bout, float* __restrict__ out, float invN) {
  __shared__ float g[HID];
  int c = threadIdx.x;
  g[c] = gsum[c] * invN;
  __syncthreads();
  float acc = bout[c];
#pragma unroll 8
  for (int k = 0; k < HID; k++) acc += g[k] * Wout[k * HID + c];
  out[c] = acc;
}

extern "C" void kernel_launch(void* const* d_in, const int* in_sizes, int n_in,
                              void* d_out, int out_size, void* d_ws, size_t ws_size,
                              hipStream_t stream) {
  const float* ns    = (const float*)d_in[0];
  const float* Win   = (const float*)d_in[1];
  const float* bin   = (const float*)d_in[2];
  const float* Wself = (const float*)d_in[3];
  const float* bself = (const float*)d_in[4];
  const float* Wnei  = (const float*)d_in[5];
  const float* bnei  = (const float*)d_in[6];
  const float* Wout  = (const float*)d_in[7];
  const float* bout  = (const float*)d_in[8];
  const int*   eidx  = (const int*)d_in[9];

  int N = in_sizes[0] / IND;
  int E = in_sizes[9] / 2;
  const int* src = eidx;
  const int* dst = eidx + E;
  int nb2 = (N + 255) >> 8;   // buckets of 256 nodes

  // ws layout: xb[N*H] bf16 | aggb[N*H] bf16 | WcT[256*512] bf16 | csr[E] i |
  //   ebuf[E] uint2 | row_start[N+1] i | bcnt[MAXB] i | bbase[MAXB+1] i |
  //   bcur[MAXB] i | gsum[H] f
  unsigned short* xb   = (unsigned short*)d_ws;
  unsigned short* aggb = xb + (size_t)N * HID;
  unsigned short* WcT  = aggb + (size_t)N * HID;
  int* csr       = (int*)(WcT + 256 * 512);
  uint2* ebuf    = (uint2*)(csr + E);
  int* row_start = (int*)(ebuf + E);
  int* bcnt      = row_start + N + 1;
  int* bbase     = bcnt + MAXB;
  int* bcur      = bbase + MAXB + 1;
  float* gsum    = (float*)(bcur + MAXB);

  hipMemsetAsync(bcnt, 0, MAXB * sizeof(int), stream);
  hipMemsetAsync(gsum, 0, HID * sizeof(float), stream);

  k_linear_in<<<(N + 7) / 8, 256, 0, stream>>>(ns, Win, bin, xb, N);
  k_wconv<<<256, 512, 0, stream>>>(Wself, Wnei, WcT);

  int pgrid = (E + PB - 1) / PB;
  k_bhist<<<pgrid, 256, 0, stream>>>(dst, bcnt, E, nb2);
  k_bscan<<<1, 512, 0, stream>>>(bcnt, bbase, bcur, row_start, E, N, nb2);
  k_part<<<pgrid, 256, 0, stream>>>(src, dst, bcur, ebuf, E, nb2);
  k_fill2<<<nb2, 256, 0, stream>>>(ebuf, bbase, row_start, csr, N);

  int agrid = (N + 3) / 4;
  k_agg<<<agrid, 256, 0, stream>>>(xb, csr, row_start, aggb, N);

  int hgrid = (N + 127) / 128;
  k_h<<<hgrid, 256, 0, stream>>>(xb, aggb, WcT, bself, bnei, gsum, N);

  k_out<<<1, HID, 0, stream>>>(gsum, Wout, bout, (float*)d_out, 1.0f / (float)N);
}

// Round 7
// 337.503 us; speedup vs baseline: 17.9933x; 1.1112x over previous
//
#include <hip/hip_runtime.h>
#include <hip/hip_bf16.h>

#define HID 256
#define IND 21
#define ASTR 40      // LDS row stride in bf16 elems (80 B): 2-way bank conflicts only
#define PB 3200      // edges per block in k_part / k_bhist
#define MAXB 512     // max buckets (N <= 131072)

typedef short short8 __attribute__((ext_vector_type(8)));
typedef float floatx4 __attribute__((ext_vector_type(4)));
typedef float floatx2 __attribute__((ext_vector_type(2)));

__device__ inline float bflo(unsigned int u) {
  union { unsigned int i; float f; } c; c.i = u << 16; return c.f;
}
__device__ inline float bfhi(unsigned int u) {
  union { unsigned int i; float f; } c; c.i = u & 0xffff0000u; return c.f;
}
__device__ inline unsigned short f2bf(float f) {
  __hip_bfloat16 h = __float2bfloat16(f);  // RNE
  union { __hip_bfloat16 h; unsigned short u; } c;
  c.h = h;
  return c.u;
}

// decode 8 fp8-e4m3 bytes -> accumulate into a[0..7]
__device__ inline void acc8_fp8(uint2 v, float* a) {
  floatx2 p;
  p = __builtin_amdgcn_cvt_pk_f32_fp8((int)v.x, false); a[0] += p.x; a[1] += p.y;
  p = __builtin_amdgcn_cvt_pk_f32_fp8((int)v.x, true);  a[2] += p.x; a[3] += p.y;
  p = __builtin_amdgcn_cvt_pk_f32_fp8((int)v.y, false); a[4] += p.x; a[5] += p.y;
  p = __builtin_amdgcn_cvt_pk_f32_fp8((int)v.y, true);  a[6] += p.x; a[7] += p.y;
}

// ---------------------------------------------------------------------------
// k1: xb = bf16(relu(ns @ W_in + b_in)); xq = fp8-e4m3 copy (gather format).
// 8 nodes/block; thread owns one output column, W_in column in registers.
// ---------------------------------------------------------------------------
__global__ __launch_bounds__(256) void k_linear_in(
    const float* __restrict__ ns, const float* __restrict__ Win,
    const float* __restrict__ bin, unsigned short* __restrict__ xb,
    unsigned int* __restrict__ xq, int N) {
  __shared__ float s[8][IND];
  __shared__ float fx[8][257];
  int nb = blockIdx.x * 8;
  int tid = threadIdx.x;
  if (tid < 8 * IND) {
    int idx = nb * IND + tid;
    s[tid / IND][tid % IND] = (idx < N * IND) ? ns[idx] : 0.f;
  }
  float w[IND];
#pragma unroll
  for (int k = 0; k < IND; k++) w[k] = Win[k * HID + tid];
  float b = bin[tid];
  __syncthreads();
#pragma unroll
  for (int j = 0; j < 8; j++) {
    int node = nb + j;
    float acc = b;
#pragma unroll
    for (int k = 0; k < IND; k++) acc += s[j][k] * w[k];
    acc = acc > 0.f ? acc : 0.f;
    fx[j][tid] = acc;
    if (node < N) xb[(size_t)node * HID + tid] = f2bf(acc);
  }
  __syncthreads();
  // pack fp8: 8 nodes x 64 words = 512 uint words, 2 per thread
#pragma unroll
  for (int t = 0; t < 2; t++) {
    int wi = tid + t * 256;
    int j = wi >> 6, cw = wi & 63;
    int node = nb + j;
    if (node < N) {
      const float* fp = &fx[j][cw * 4];
      int lo = __builtin_amdgcn_cvt_pk_fp8_f32(fp[0], fp[1], 0, false);
      int full = __builtin_amdgcn_cvt_pk_fp8_f32(fp[2], fp[3], lo, true);
      xq[(size_t)node * 64 + cw] = (unsigned int)full;
    }
  }
}

// ---------------------------------------------------------------------------
// weight prep: WcT[n][k] = bf16( k<256 ? Wself[k][n] : Wnei[k-256][n] )
// ---------------------------------------------------------------------------
__global__ __launch_bounds__(512) void k_wconv(
    const float* __restrict__ Wself, const float* __restrict__ Wnei,
    unsigned short* __restrict__ WcT) {
  int n = blockIdx.x;
  int k = threadIdx.x;
  float v = (k < HID) ? Wself[k * HID + n] : Wnei[(k - HID) * HID + n];
  WcT[n * 512 + k] = f2bf(v);
}

// ---------------------------------------------------------------------------
// CSR build: bucket hist -> bucket scan -> partition -> per-bucket scan+fill
// bucket = dst >> 8 (256 nodes per bucket)
// ---------------------------------------------------------------------------
__global__ __launch_bounds__(256) void k_bhist(
    const int* __restrict__ dst, int* __restrict__ bcnt, int E, int nb2) {
  __shared__ int lh[MAXB];
  int tid = threadIdx.x;
  int e0 = blockIdx.x * PB;
  for (int b = tid; b < nb2; b += 256) lh[b] = 0;
  __syncthreads();
  int c = min(PB, E - e0);
  for (int i = tid; i < c; i += 256) atomicAdd(&lh[dst[e0 + i] >> 8], 1);
  __syncthreads();
  for (int b = tid; b < nb2; b += 256)
    if (lh[b]) atomicAdd(&bcnt[b], lh[b]);
}

__global__ __launch_bounds__(512) void k_bscan(
    const int* __restrict__ bcnt, int* __restrict__ bbase, int* __restrict__ bcur,
    int* __restrict__ row_start, int E, int N, int nb2) {
  __shared__ int ts[512];
  int tid = threadIdx.x;
  int v = (tid < nb2) ? bcnt[tid] : 0;
  ts[tid] = v;
  __syncthreads();
  for (int off = 1; off < 512; off <<= 1) {
    int t = (tid >= off) ? ts[tid - off] : 0;
    __syncthreads();
    ts[tid] += t;
    __syncthreads();
  }
  if (tid < nb2) { bbase[tid] = ts[tid] - v; bcur[tid] = ts[tid] - v; }
  if (tid == 0) { bbase[nb2] = E; row_start[N] = E; }
}

// partition edges into per-bucket regions of ebuf. LDS histogram -> one global
// reservation per (block,bucket) -> dense 8B writes (src/dst re-read, L2-hot).
__global__ __launch_bounds__(256) void k_part(
    const int* __restrict__ src, const int* __restrict__ dst,
    int* __restrict__ bcur, uint2* __restrict__ ebuf, int E, int nb2) {
  __shared__ int lh[MAXB];
  int tid = threadIdx.x;
  int e0 = blockIdx.x * PB;
  for (int b = tid; b < nb2; b += 256) lh[b] = 0;
  __syncthreads();
  int cnt = min(PB, E - e0);
  for (int i = tid; i < cnt; i += 256) atomicAdd(&lh[dst[e0 + i] >> 8], 1);
  __syncthreads();
  for (int b = tid; b < nb2; b += 256) {
    int c = lh[b];
    lh[b] = (c > 0) ? atomicAdd(&bcur[b], c) : 0;
  }
  __syncthreads();
  for (int i = tid; i < cnt; i += 256) {
    int s = src[e0 + i];
    int d = dst[e0 + i];
    int pos = atomicAdd(&lh[d >> 8], 1);
    ebuf[pos] = make_uint2((unsigned)s, (unsigned)d);
  }
}

// one block per bucket: LDS count + scan -> row_start; LDS cursors -> csr.
__global__ __launch_bounds__(256) void k_fill2(
    const uint2* __restrict__ ebuf, const int* __restrict__ bbase,
    int* __restrict__ row_start, int* __restrict__ csr, int N) {
  __shared__ int lcnt[256];
  __shared__ int lcur[256];
  __shared__ int ts[256];
  int b = blockIdx.x;
  int tid = threadIdx.x;
  int start = bbase[b], end = bbase[b + 1];
  lcnt[tid] = 0;
  __syncthreads();
  for (int i = start + tid; i < end; i += 256)
    atomicAdd(&lcnt[ebuf[i].y & 255], 1);
  __syncthreads();
  int v = lcnt[tid];
  ts[tid] = v;
  __syncthreads();
  for (int off = 1; off < 256; off <<= 1) {
    int t = (tid >= off) ? ts[tid - off] : 0;
    __syncthreads();
    ts[tid] += t;
    __syncthreads();
  }
  int excl = start + ts[tid] - v;
  int node = (b << 8) + tid;
  if (node < N) row_start[node] = excl;
  lcur[tid] = excl;
  __syncthreads();
  for (int i = start + tid; i < end; i += 256) {
    uint2 e = ebuf[i];
    int pos = atomicAdd(&lcur[e.y & 255], 1);
    csr[pos] = (int)e.x;
  }
}

// ---------------------------------------------------------------------------
// k_agg: one wave per node; fp8 gather (32 lanes x 8 B = 256 B row), 4 edges
// per iteration (2 independent loads per 32-lane half). fp32 accumulate;
// halves combined via shfl_xor; bf16 mean written by lower half.
// ---------------------------------------------------------------------------
__global__ __launch_bounds__(256) void k_agg(
    const uint2* __restrict__ xq, const int* __restrict__ csr,
    const int* __restrict__ row_start, unsigned short* __restrict__ aggb, int N) {
  int wid = (int)((blockIdx.x * (unsigned)blockDim.x + threadIdx.x) >> 6);
  int lane = threadIdx.x & 63;
  int half = lane >> 5;
  int l32 = lane & 31;
  if (wid >= N) return;
  int start = row_start[wid];
  int end = row_start[wid + 1];
  int c = end - start;
  float a[8], b2[8];
#pragma unroll
  for (int j = 0; j < 8; j++) { a[j] = 0.f; b2[j] = 0.f; }

  int i = 0;
  for (; i + 4 <= c; i += 4) {
    int s0 = csr[start + i + half];
    int s1 = csr[start + i + 2 + half];
    uint2 v0 = xq[(size_t)s0 * 32 + l32];
    uint2 v1 = xq[(size_t)s1 * 32 + l32];
    acc8_fp8(v0, a);
    acc8_fp8(v1, b2);
  }
  if (i + 2 <= c) {
    int s0 = csr[start + i + half];
    uint2 v0 = xq[(size_t)s0 * 32 + l32];
    acc8_fp8(v0, a);
    i += 2;
  }
  if ((c & 1) && half == 0) {
    int s0 = csr[start + c - 1];
    uint2 v0 = xq[(size_t)s0 * 32 + l32];
    acc8_fp8(v0, a);
  }
#pragma unroll
  for (int j = 0; j < 8; j++) a[j] += b2[j];
#pragma unroll
  for (int j = 0; j < 8; j++) a[j] += __shfl_xor(a[j], 32);

  if (half == 0) {
    float inv = 1.0f / fmaxf((float)c, 1.0f);
    uint4 o;
    o.x = ((unsigned int)f2bf(a[1] * inv) << 16) | f2bf(a[0] * inv);
    o.y = ((unsigned int)f2bf(a[3] * inv) << 16) | f2bf(a[2] * inv);
    o.z = ((unsigned int)f2bf(a[5] * inv) << 16) | f2bf(a[4] * inv);
    o.w = ((unsigned int)f2bf(a[7] * inv) << 16) | f2bf(a[6] * inv);
    *(uint4*)&aggb[(size_t)wid * HID + l32 * 8] = o;
  }
}

// ---------------------------------------------------------------------------
// k_h: gsum[c] += sum_rows relu( [x|agg] @ WcT^T + bself + bnei )
// 128 rows x 256 cols per block (A staged exactly once). 4 waves 2x2;
// wave = 64 rows x 128 cols; B frags just-in-time. MFMA bf16 16x16x32.
// ---------------------------------------------------------------------------
__global__ __launch_bounds__(256, 2) void k_h(
    const unsigned short* __restrict__ xb, const unsigned short* __restrict__ aggb,
    const unsigned short* __restrict__ WcT, const float* __restrict__ bself,
    const float* __restrict__ bnei, float* __restrict__ gsum, int N) {
  __shared__ __align__(16) unsigned short As[128 * ASTR];
  __shared__ __align__(16) unsigned short Bs[256 * ASTR];
  __shared__ float colsum[256];
  int tid = threadIdx.x;
  int rowBase = blockIdx.x * 128;
  int lane = tid & 63;
  int wid = tid >> 6;
  int wr = wid >> 1, wc = wid & 1;
  int n16 = lane & 15, quad = lane >> 4;

  colsum[tid] = 0.f;

  floatx4 acc[4][8];
#pragma unroll
  for (int i = 0; i < 4; i++)
#pragma unroll
    for (int j = 0; j < 8; j++) acc[i][j] = (floatx4){0.f, 0.f, 0.f, 0.f};

  for (int k0 = 0; k0 < 512; k0 += 32) {
    const unsigned short* abase = (k0 < HID) ? xb : aggb;
    int kc = (k0 < HID) ? k0 : (k0 - HID);
#pragma unroll
    for (int j = 0; j < 2; j++) {
      int idx = tid + j * 256;
      int r = idx >> 2;
      int s = idx & 3;
      int gr = rowBase + r;
      if (gr >= N) gr = N - 1;
      uint4 va = *(const uint4*)(abase + (size_t)gr * HID + kc + s * 8);
      *(uint4*)(&As[r * ASTR + s * 8]) = va;
    }
#pragma unroll
    for (int j = 0; j < 4; j++) {
      int idx = tid + j * 256;
      int r = idx >> 2;
      int s = idx & 3;
      uint4 vb = *(const uint4*)(WcT + (size_t)r * 512 + k0 + s * 8);
      *(uint4*)(&Bs[r * ASTR + s * 8]) = vb;
    }
    __syncthreads();

    short8 af[4];
#pragma unroll
    for (int rt = 0; rt < 4; rt++)
      af[rt] = *(const short8*)&As[(wr * 64 + rt * 16 + n16) * ASTR + quad * 8];
#pragma unroll
    for (int ct = 0; ct < 8; ct++) {
      short8 bf = *(const short8*)&Bs[(wc * 128 + ct * 16 + n16) * ASTR + quad * 8];
#pragma unroll
      for (int rt = 0; rt < 4; rt++)
        acc[rt][ct] = __builtin_amdgcn_mfma_f32_16x16x32_bf16(
            af[rt], bf, acc[rt][ct], 0, 0, 0);
    }
    __syncthreads();
  }

#pragma unroll
  for (int ct = 0; ct < 8; ct++) {
    int gcol = wc * 128 + ct * 16 + n16;
    float bb = bself[gcol] + bnei[gcol];
    float psum = 0.f;
#pragma unroll
    for (int rt = 0; rt < 4; rt++) {
#pragma unroll
      for (int r = 0; r < 4; r++) {
        int row = rowBase + wr * 64 + rt * 16 + quad * 4 + r;
        float v = acc[rt][ct][r] + bb;
        v = v > 0.f ? v : 0.f;
        if (row < N) psum += v;
      }
    }
    atomicAdd(&colsum[gcol], psum);
  }
  __syncthreads();
  atomicAdd(&gsum[tid], colsum[tid]);
}

// ---------------------------------------------------------------------------
// k_out: out = (gsum / N) @ W_out + b_out   single block, 256 threads
// ---------------------------------------------------------------------------
__global__ __launch_bounds__(HID) void k_out(
    const float* __restrict__ gsum, const float* __restrict__ Wout,
    const float* __restrict__ bout, float* __restrict__ out, float invN) {
  __shared__ float g[HID];
  int c = threadIdx.x;
  g[c] = gsum[c] * invN;
  __syncthreads();
  float acc = bout[c];
#pragma unroll 8
  for (int k = 0; k < HID; k++) acc += g[k] * Wout[k * HID + c];
  out[c] = acc;
}

extern "C" void kernel_launch(void* const* d_in, const int* in_sizes, int n_in,
                              void* d_out, int out_size, void* d_ws, size_t ws_size,
                              hipStream_t stream) {
  const float* ns    = (const float*)d_in[0];
  const float* Win   = (const float*)d_in[1];
  const float* bin   = (const float*)d_in[2];
  const float* Wself = (const float*)d_in[3];
  const float* bself = (const float*)d_in[4];
  const float* Wnei  = (const float*)d_in[5];
  const float* bnei  = (const float*)d_in[6];
  const float* Wout  = (const float*)d_in[7];
  const float* bout  = (const float*)d_in[8];
  const int*   eidx  = (const int*)d_in[9];

  int N = in_sizes[0] / IND;
  int E = in_sizes[9] / 2;
  const int* src = eidx;
  const int* dst = eidx + E;
  int nb2 = (N + 255) >> 8;

  // ws layout: xb[N*H] bf16 | aggb[N*H] bf16 | xq[N*64] uint | WcT bf16 |
  //   csr[E] i | ebuf[E] uint2 | row_start[N+1] i | bcnt | bbase | bcur | gsum
  unsigned short* xb   = (unsigned short*)d_ws;
  unsigned short* aggb = xb + (size_t)N * HID;
  unsigned int* xq     = (unsigned int*)(aggb + (size_t)N * HID);
  unsigned short* WcT  = (unsigned short*)(xq + (size_t)N * 64);
  int* csr       = (int*)(WcT + 256 * 512);
  uint2* ebuf    = (uint2*)(csr + E);
  int* row_start = (int*)(ebuf + E);
  int* bcnt      = row_start + N + 1;
  int* bbase     = bcnt + MAXB;
  int* bcur      = bbase + MAXB + 1;
  float* gsum    = (float*)(bcur + MAXB);

  hipMemsetAsync(bcnt, 0, MAXB * sizeof(int), stream);
  hipMemsetAsync(gsum, 0, HID * sizeof(float), stream);

  k_linear_in<<<(N + 7) / 8, 256, 0, stream>>>(ns, Win, bin, xb, xq, N);
  k_wconv<<<256, 512, 0, stream>>>(Wself, Wnei, WcT);

  int pgrid = (E + PB - 1) / PB;
  k_bhist<<<pgrid, 256, 0, stream>>>(dst, bcnt, E, nb2);
  k_bscan<<<1, 512, 0, stream>>>(bcnt, bbase, bcur, row_start, E, N, nb2);
  k_part<<<pgrid, 256, 0, stream>>>(src, dst, bcur, ebuf, E, nb2);
  k_fill2<<<nb2, 256, 0, stream>>>(ebuf, bbase, row_start, csr, N);

  int agrid = (N + 3) / 4;
  k_agg<<<agrid, 256, 0, stream>>>((const uint2*)xq, csr, row_start, aggb, N);

  int hgrid = (N + 127) / 128;
  k_h<<<hgrid, 256, 0, stream>>>(xb, aggb, WcT, bself, bnei, gsum, N);

  k_out<<<1, HID, 0, stream>>>(gsum, Wout, bout, (float*)d_out, 1.0f / (float)N);
}

// Round 8
// 322.012 us; speedup vs baseline: 18.8590x; 1.0481x over previous
//
#include <hip/hip_runtime.h>
#include <hip/hip_bf16.h>

#define HID 256
#define IND 21
#define ASTR 40      // LDS row stride in bf16 elems (80 B): 2-way bank conflicts only
#define PB 3200      // edges per block in k_part / bhist
#define MAXB 512     // max buckets (N <= 131072)

typedef short short8 __attribute__((ext_vector_type(8)));
typedef float floatx4 __attribute__((ext_vector_type(4)));
typedef float floatx2 __attribute__((ext_vector_type(2)));

__device__ inline unsigned short f2bf(float f) {
  __hip_bfloat16 h = __float2bfloat16(f);  // RNE
  union { __hip_bfloat16 h; unsigned short u; } c;
  c.h = h;
  return c.u;
}

// pack float2 -> 2 bf16 by truncation (exact for values that came from fp8)
__device__ inline unsigned int pk_bf16_trunc(floatx2 p) {
  union { float f; unsigned int u; } a, b;
  a.f = p.x; b.f = p.y;
  return (b.u & 0xffff0000u) | (a.u >> 16);
}

// accumulate 8 fp8 bytes into 4 packed-f32 accumulators
__device__ inline void acc8p(uint2 v, floatx2* a) {
  a[0] += __builtin_amdgcn_cvt_pk_f32_fp8((int)v.x, false);
  a[1] += __builtin_amdgcn_cvt_pk_f32_fp8((int)v.x, true);
  a[2] += __builtin_amdgcn_cvt_pk_f32_fp8((int)v.y, false);
  a[3] += __builtin_amdgcn_cvt_pk_f32_fp8((int)v.y, true);
}

// ---------------------------------------------------------------------------
// fused front kernel: [0,G1) linear_in | [G1,G1+256) wconv | rest bhist
// All three are independent; fusing saves launch gaps.
// ---------------------------------------------------------------------------
__global__ __launch_bounds__(256) void k_front(
    const float* __restrict__ ns, const float* __restrict__ Win,
    const float* __restrict__ bin, unsigned int* __restrict__ xq,
    const float* __restrict__ Wself, const float* __restrict__ Wnei,
    unsigned short* __restrict__ WcT,
    const int* __restrict__ dst, int* __restrict__ bcnt,
    int N, int E, int nb2, int G1) {
  int blk = blockIdx.x;
  int tid = threadIdx.x;
  if (blk < G1) {
    // ---- linear_in: xq = fp8(relu(ns @ W_in + b_in)), 8 nodes/block ----
    __shared__ float s[8][IND];
    __shared__ float fx[8][257];
    int nb = blk * 8;
    if (tid < 8 * IND) {
      int idx = nb * IND + tid;
      s[tid / IND][tid % IND] = (idx < N * IND) ? ns[idx] : 0.f;
    }
    float w[IND];
#pragma unroll
    for (int k = 0; k < IND; k++) w[k] = Win[k * HID + tid];
    float b = bin[tid];
    __syncthreads();
#pragma unroll
    for (int j = 0; j < 8; j++) {
      float acc = b;
#pragma unroll
      for (int k = 0; k < IND; k++) acc += s[j][k] * w[k];
      fx[j][tid] = acc > 0.f ? acc : 0.f;
    }
    __syncthreads();
#pragma unroll
    for (int t = 0; t < 2; t++) {
      int wi = tid + t * 256;
      int j = wi >> 6, cw = wi & 63;
      int node = nb + j;
      if (node < N) {
        const float* fp = &fx[j][cw * 4];
        int lo = __builtin_amdgcn_cvt_pk_fp8_f32(fp[0], fp[1], 0, false);
        int full = __builtin_amdgcn_cvt_pk_fp8_f32(fp[2], fp[3], lo, true);
        xq[(size_t)node * 64 + cw] = (unsigned int)full;
      }
    }
  } else if (blk < G1 + 256) {
    // ---- wconv: WcT[n][k] = bf16(k<256 ? Wself[k][n] : Wnei[k-256][n]) ----
    int n = blk - G1;
#pragma unroll
    for (int t = 0; t < 2; t++) {
      int k = tid + t * 256;
      float v = (k < HID) ? Wself[k * HID + n] : Wnei[(k - HID) * HID + n];
      WcT[n * 512 + k] = f2bf(v);
    }
  } else {
    // ---- bhist: bucket histogram of dst ----
    __shared__ int lh[MAXB];
    int e0 = (blk - G1 - 256) * PB;
    for (int b = tid; b < nb2; b += 256) lh[b] = 0;
    __syncthreads();
    int c = min(PB, E - e0);
    for (int i = tid; i < c; i += 256) atomicAdd(&lh[dst[e0 + i] >> 8], 1);
    __syncthreads();
    for (int b = tid; b < nb2; b += 256)
      if (lh[b]) atomicAdd(&bcnt[b], lh[b]);
  }
}

__global__ __launch_bounds__(512) void k_bscan(
    const int* __restrict__ bcnt, int* __restrict__ bbase, int* __restrict__ bcur,
    int* __restrict__ row_start, int E, int N, int nb2) {
  __shared__ int ts[512];
  int tid = threadIdx.x;
  int v = (tid < nb2) ? bcnt[tid] : 0;
  ts[tid] = v;
  __syncthreads();
  for (int off = 1; off < 512; off <<= 1) {
    int t = (tid >= off) ? ts[tid - off] : 0;
    __syncthreads();
    ts[tid] += t;
    __syncthreads();
  }
  if (tid < nb2) { bbase[tid] = ts[tid] - v; bcur[tid] = ts[tid] - v; }
  if (tid == 0) { bbase[nb2] = E; row_start[N] = E; }
}

// partition edges into per-bucket regions of ebuf (bucket = dst>>8)
__global__ __launch_bounds__(256) void k_part(
    const int* __restrict__ src, const int* __restrict__ dst,
    int* __restrict__ bcur, uint2* __restrict__ ebuf, int E, int nb2) {
  __shared__ int lh[MAXB];
  int tid = threadIdx.x;
  int e0 = blockIdx.x * PB;
  for (int b = tid; b < nb2; b += 256) lh[b] = 0;
  __syncthreads();
  int cnt = min(PB, E - e0);
  for (int i = tid; i < cnt; i += 256) atomicAdd(&lh[dst[e0 + i] >> 8], 1);
  __syncthreads();
  for (int b = tid; b < nb2; b += 256) {
    int c = lh[b];
    lh[b] = (c > 0) ? atomicAdd(&bcur[b], c) : 0;
  }
  __syncthreads();
  for (int i = tid; i < cnt; i += 256) {
    int s = src[e0 + i];
    int d = dst[e0 + i];
    int pos = atomicAdd(&lh[d >> 8], 1);
    ebuf[pos] = make_uint2((unsigned)s, (unsigned)d);
  }
}

// one block per bucket: LDS count + scan -> row_start; LDS cursors -> csr.
__global__ __launch_bounds__(256) void k_fill2(
    const uint2* __restrict__ ebuf, const int* __restrict__ bbase,
    int* __restrict__ row_start, int* __restrict__ csr, int N) {
  __shared__ int lcnt[256];
  __shared__ int lcur[256];
  __shared__ int ts[256];
  int b = blockIdx.x;
  int tid = threadIdx.x;
  int start = bbase[b], end = bbase[b + 1];
  lcnt[tid] = 0;
  __syncthreads();
  for (int i = start + tid; i < end; i += 256)
    atomicAdd(&lcnt[ebuf[i].y & 255], 1);
  __syncthreads();
  int v = lcnt[tid];
  ts[tid] = v;
  __syncthreads();
  for (int off = 1; off < 256; off <<= 1) {
    int t = (tid >= off) ? ts[tid - off] : 0;
    __syncthreads();
    ts[tid] += t;
    __syncthreads();
  }
  int excl = start + ts[tid] - v;
  int node = (b << 8) + tid;
  if (node < N) row_start[node] = excl;
  lcur[tid] = excl;
  __syncthreads();
  for (int i = start + tid; i < end; i += 256) {
    uint2 e = ebuf[i];
    int pos = atomicAdd(&lcur[e.y & 255], 1);
    csr[pos] = (int)e.x;
  }
}

// ---------------------------------------------------------------------------
// k_agg: one wave per node; fp8 gather (32 lanes x 8 B = 256 B row), 8 edges
// per iteration (4 independent loads per 32-lane half), packed-f32 adds.
// Halves combined via shfl_xor; fp8 mean written by lower half.
// ---------------------------------------------------------------------------
__global__ __launch_bounds__(256) void k_agg(
    const uint2* __restrict__ xq, const int* __restrict__ csr,
    const int* __restrict__ row_start, uint2* __restrict__ aggq, int N) {
  int wid = (int)((blockIdx.x * (unsigned)blockDim.x + threadIdx.x) >> 6);
  int lane = threadIdx.x & 63;
  int half = lane >> 5;
  int l32 = lane & 31;
  if (wid >= N) return;
  int start = row_start[wid];
  int end = row_start[wid + 1];
  int c = end - start;
  floatx2 a[4], b[4], d[4], e[4];
#pragma unroll
  for (int j = 0; j < 4; j++) {
    a[j] = (floatx2){0.f, 0.f}; b[j] = (floatx2){0.f, 0.f};
    d[j] = (floatx2){0.f, 0.f}; e[j] = (floatx2){0.f, 0.f};
  }

  int i = 0;
  for (; i + 8 <= c; i += 8) {
    int s0 = csr[start + i + half];
    int s1 = csr[start + i + 2 + half];
    int s2 = csr[start + i + 4 + half];
    int s3 = csr[start + i + 6 + half];
    uint2 v0 = xq[(size_t)s0 * 32 + l32];
    uint2 v1 = xq[(size_t)s1 * 32 + l32];
    uint2 v2 = xq[(size_t)s2 * 32 + l32];
    uint2 v3 = xq[(size_t)s3 * 32 + l32];
    acc8p(v0, a); acc8p(v1, b); acc8p(v2, d); acc8p(v3, e);
  }
  for (; i + 2 <= c; i += 2) {
    int s0 = csr[start + i + half];
    uint2 v0 = xq[(size_t)s0 * 32 + l32];
    acc8p(v0, a);
  }
  if ((c & 1) && half == 0) {
    int s0 = csr[start + c - 1];
    uint2 v0 = xq[(size_t)s0 * 32 + l32];
    acc8p(v0, a);
  }
#pragma unroll
  for (int j = 0; j < 4; j++) a[j] += b[j] + d[j] + e[j];

  float f[8];
#pragma unroll
  for (int j = 0; j < 4; j++) { f[2 * j] = a[j].x; f[2 * j + 1] = a[j].y; }
#pragma unroll
  for (int j = 0; j < 8; j++) f[j] += __shfl_xor(f[j], 32);

  if (half == 0) {
    float inv = 1.0f / fmaxf((float)c, 1.0f);
#pragma unroll
    for (int j = 0; j < 8; j++) f[j] *= inv;
    int lo0 = __builtin_amdgcn_cvt_pk_fp8_f32(f[0], f[1], 0, false);
    int w0  = __builtin_amdgcn_cvt_pk_fp8_f32(f[2], f[3], lo0, true);
    int lo1 = __builtin_amdgcn_cvt_pk_fp8_f32(f[4], f[5], 0, false);
    int w1  = __builtin_amdgcn_cvt_pk_fp8_f32(f[6], f[7], lo1, true);
    aggq[(size_t)wid * 32 + l32] = make_uint2((unsigned)w0, (unsigned)w1);
  }
}

// ---------------------------------------------------------------------------
// k_h: gsum[c] += sum_rows relu( [x|agg] @ WcT^T + bself + bnei )
// A sourced from fp8 (xq / aggq), decoded to bf16 during LDS staging
// (fp8 -> bf16 is exact). 128 rows x 256 cols per block; 4 waves 2x2;
// MFMA bf16 16x16x32; B frags just-in-time.
// ---------------------------------------------------------------------------
__global__ __launch_bounds__(256, 2) void k_h(
    const unsigned char* __restrict__ xq8, const unsigned char* __restrict__ aggq8,
    const unsigned short* __restrict__ WcT, const float* __restrict__ bself,
    const float* __restrict__ bnei, float* __restrict__ gsum, int N) {
  __shared__ __align__(16) unsigned short As[128 * ASTR];
  __shared__ __align__(16) unsigned short Bs[256 * ASTR];
  __shared__ float colsum[256];
  int tid = threadIdx.x;
  int rowBase = blockIdx.x * 128;
  int lane = tid & 63;
  int wid = tid >> 6;
  int wr = wid >> 1, wc = wid & 1;
  int n16 = lane & 15, quad = lane >> 4;

  colsum[tid] = 0.f;

  floatx4 acc[4][8];
#pragma unroll
  for (int i = 0; i < 4; i++)
#pragma unroll
    for (int j = 0; j < 8; j++) acc[i][j] = (floatx4){0.f, 0.f, 0.f, 0.f};

  int ar = tid >> 1;          // 0..127: A row this thread stages
  int as = tid & 1;           // 16-byte segment (16 fp8 values)
  int gr = rowBase + ar;
  if (gr >= N) gr = N - 1;

  for (int k0 = 0; k0 < 512; k0 += 32) {
    const unsigned char* abase = (k0 < HID) ? xq8 : aggq8;
    int kc = k0 & 255;
    // stage A: 128 rows x 32 fp8 = 4 KB; 1 uint4 (16 vals) per thread,
    // decode fp8 -> bf16 (exact) into As
    uint4 v = *(const uint4*)(abase + (size_t)gr * HID + kc + as * 16);
    unsigned int w[8];
    {
      unsigned int src4[4] = {v.x, v.y, v.z, v.w};
#pragma unroll
      for (int j = 0; j < 4; j++) {
        floatx2 p0 = __builtin_amdgcn_cvt_pk_f32_fp8((int)src4[j], false);
        floatx2 p1 = __builtin_amdgcn_cvt_pk_f32_fp8((int)src4[j], true);
        w[2 * j] = pk_bf16_trunc(p0);
        w[2 * j + 1] = pk_bf16_trunc(p1);
      }
    }
    *(uint4*)(&As[ar * ASTR + as * 16]) = make_uint4(w[0], w[1], w[2], w[3]);
    *(uint4*)(&As[ar * ASTR + as * 16 + 8]) = make_uint4(w[4], w[5], w[6], w[7]);
    // stage B: 256 cols x 32 k bf16 = 1024 uint4 -> 4/thread
#pragma unroll
    for (int j = 0; j < 4; j++) {
      int idx = tid + j * 256;
      int r = idx >> 2;
      int s = idx & 3;
      uint4 vb = *(const uint4*)(WcT + (size_t)r * 512 + k0 + s * 8);
      *(uint4*)(&Bs[r * ASTR + s * 8]) = vb;
    }
    __syncthreads();

    short8 af[4];
#pragma unroll
    for (int rt = 0; rt < 4; rt++)
      af[rt] = *(const short8*)&As[(wr * 64 + rt * 16 + n16) * ASTR + quad * 8];
#pragma unroll
    for (int ct = 0; ct < 8; ct++) {
      short8 bf = *(const short8*)&Bs[(wc * 128 + ct * 16 + n16) * ASTR + quad * 8];
#pragma unroll
      for (int rt = 0; rt < 4; rt++)
        acc[rt][ct] = __builtin_amdgcn_mfma_f32_16x16x32_bf16(
            af[rt], bf, acc[rt][ct], 0, 0, 0);
    }
    __syncthreads();
  }

  // epilogue: bias + relu + row-masked column sums (C/D: col=lane&15, row=quad*4+reg)
#pragma unroll
  for (int ct = 0; ct < 8; ct++) {
    int gcol = wc * 128 + ct * 16 + n16;
    float bb = bself[gcol] + bnei[gcol];
    float psum = 0.f;
#pragma unroll
    for (int rt = 0; rt < 4; rt++) {
#pragma unroll
      for (int r = 0; r < 4; r++) {
        int row = rowBase + wr * 64 + rt * 16 + quad * 4 + r;
        float v = acc[rt][ct][r] + bb;
        v = v > 0.f ? v : 0.f;
        if (row < N) psum += v;
      }
    }
    atomicAdd(&colsum[gcol], psum);
  }
  __syncthreads();
  atomicAdd(&gsum[tid], colsum[tid]);
}

// ---------------------------------------------------------------------------
// k_out: out = (gsum / N) @ W_out + b_out   single block, 256 threads
// ---------------------------------------------------------------------------
__global__ __launch_bounds__(HID) void k_out(
    const float* __restrict__ gsum, const float* __restrict__ Wout,
    const float* __restrict__ bout, float* __restrict__ out, float invN) {
  __shared__ float g[HID];
  int c = threadIdx.x;
  g[c] = gsum[c] * invN;
  __syncthreads();
  float acc = bout[c];
#pragma unroll 8
  for (int k = 0; k < HID; k++) acc += g[k] * Wout[k * HID + c];
  out[c] = acc;
}

extern "C" void kernel_launch(void* const* d_in, const int* in_sizes, int n_in,
                              void* d_out, int out_size, void* d_ws, size_t ws_size,
                              hipStream_t stream) {
  const float* ns    = (const float*)d_in[0];
  const float* Win   = (const float*)d_in[1];
  const float* bin   = (const float*)d_in[2];
  const float* Wself = (const float*)d_in[3];
  const float* bself = (const float*)d_in[4];
  const float* Wnei  = (const float*)d_in[5];
  const float* bnei  = (const float*)d_in[6];
  const float* Wout  = (const float*)d_in[7];
  const float* bout  = (const float*)d_in[8];
  const int*   eidx  = (const int*)d_in[9];

  int N = in_sizes[0] / IND;
  int E = in_sizes[9] / 2;
  const int* src = eidx;
  const int* dst = eidx + E;
  int nb2 = (N + 255) >> 8;

  // ws layout: xq[N*64] uint | aggq[N*64] uint | WcT[256*512] bf16 | csr[E] i |
  //   ebuf[E] uint2 | row_start[N+1] i | bcnt | bbase | bcur | gsum
  unsigned int* xq    = (unsigned int*)d_ws;
  unsigned int* aggq  = xq + (size_t)N * 64;
  unsigned short* WcT = (unsigned short*)(aggq + (size_t)N * 64);
  int* csr       = (int*)(WcT + 256 * 512);
  uint2* ebuf    = (uint2*)(csr + E);
  int* row_start = (int*)(ebuf + E);
  int* bcnt      = row_start + N + 1;
  int* bbase     = bcnt + MAXB;
  int* bcur      = bbase + MAXB + 1;
  float* gsum    = (float*)(bcur + MAXB);

  hipMemsetAsync(bcnt, 0, MAXB * sizeof(int), stream);
  hipMemsetAsync(gsum, 0, HID * sizeof(float), stream);

  int G1 = (N + 7) / 8;
  int pgrid = (E + PB - 1) / PB;
  k_front<<<G1 + 256 + pgrid, 256, 0, stream>>>(
      ns, Win, bin, xq, Wself, Wnei, WcT, dst, bcnt, N, E, nb2, G1);

  k_bscan<<<1, 512, 0, stream>>>(bcnt, bbase, bcur, row_start, E, N, nb2);
  k_part<<<pgrid, 256, 0, stream>>>(src, dst, bcur, ebuf, E, nb2);
  k_fill2<<<nb2, 256, 0, stream>>>(ebuf, bbase, row_start, csr, N);

  int agrid = (N + 3) / 4;
  k_agg<<<agrid, 256, 0, stream>>>((const uint2*)xq, csr, row_start,
                                   (uint2*)aggq, N);

  int hgrid = (N + 127) / 128;
  k_h<<<hgrid, 256, 0, stream>>>((const unsigned char*)xq,
                                 (const unsigned char*)aggq,
                                 WcT, bself, bnei, gsum, N);

  k_out<<<1, HID, 0, stream>>>(gsum, Wout, bout, (float*)d_out, 1.0f / (float)N);
}